// Round 1
// baseline (822.525 us; speedup 1.0000x reference)
//
#include <hip/hip_runtime.h>
#include <hip/hip_bf16.h>
#include <cmath>

// Problem constants (B=8, H=W=112, C=192, heads=8, hd=24, ps=7, hid=768)
#define C_DIM 192
#define HID 768

typedef __attribute__((ext_vector_type(8))) __bf16 bf16x8;
typedef __attribute__((ext_vector_type(4))) float f32x4;
typedef __attribute__((ext_vector_type(2))) float f32x2;

__device__ __forceinline__ void gload_lds16(const void* g, void* l) {
  __builtin_amdgcn_global_load_lds(
      (__attribute__((address_space(1))) void*)(const_cast<void*>(g)),
      (__attribute__((address_space(3))) void*)(l), 16, 0, 0);
}

__device__ __forceinline__ float bfu2f(ushort u) {
  return __uint_as_float((unsigned)u << 16);
}
__device__ __forceinline__ ushort f2bfu(float f) {
  __hip_bfloat16 h = __float2bfloat16(f);
  return *reinterpret_cast<ushort*>(&h);
}
// tanh-form GELU: |err| ~3e-4 << bf16 ulp (validated R5, absmax 0.0156)
__device__ __forceinline__ float fgelu(float x) {
  float z = x * (1.5957691216f + 0.071354816f * x * x);
  return x / (1.f + __expf(-z));
}

// ---------------- prep: weights fp32 -> bf16 (+ fold q scale) ----------------
__global__ __launch_bounds__(256) void prep_kernel(
    const float* __restrict__ q_w, const float* __restrict__ q_b,
    const float* __restrict__ kv_w, const float* __restrict__ kv_b,
    const float* __restrict__ proj_w, const float* __restrict__ fc1_w,
    const float* __restrict__ fc2_w,
    __hip_bfloat16* __restrict__ wcat, float* __restrict__ bcat,
    __hip_bfloat16* __restrict__ projw, __hip_bfloat16* __restrict__ fc1w,
    __hip_bfloat16* __restrict__ fc2w)
{
  int idx = blockIdx.x * 256 + threadIdx.x;
  const float scale = 0.20412414523193154f;  // 24^-0.5
  if (idx < 110592) {
    float v = (idx < 36864) ? q_w[idx] * scale : kv_w[idx - 36864];
    wcat[idx] = __float2bfloat16(v);
  }
  if (idx < 576) bcat[idx] = (idx < 192) ? q_b[idx] * scale : kv_b[idx - 192];
  if (idx < 36864) projw[idx] = __float2bfloat16(proj_w[idx]);
  if (idx < 147456) {
    fc1w[idx] = __float2bfloat16(fc1_w[idx]);
    fc2w[idx] = __float2bfloat16(fc2_w[idx]);
  }
}

// -------- LayerNorm fp32 -> bf16, one wave per token (192 = 64*3) -----------
__global__ __launch_bounds__(256) void ln_kernel(
    const float* __restrict__ x, const float* __restrict__ g,
    const float* __restrict__ b, __hip_bfloat16* __restrict__ out)
{
  int t = blockIdx.x * 4 + (threadIdx.x >> 6);
  int lane = threadIdx.x & 63;
  const float* xr = x + (size_t)t * C_DIM;
  float v0 = xr[lane], v1 = xr[lane + 64], v2 = xr[lane + 128];
  float s = v0 + v1 + v2;
  float sq = v0 * v0 + v1 * v1 + v2 * v2;
  #pragma unroll
  for (int off = 32; off > 0; off >>= 1) {
    s += __shfl_xor(s, off, 64);
    sq += __shfl_xor(sq, off, 64);
  }
  float mean = s * (1.0f / 192.0f);
  float var = sq * (1.0f / 192.0f) - mean * mean;
  float rstd = rsqrtf(var + 1e-5f);
  size_t o = (size_t)t * C_DIM;
  out[o + lane]       = __float2bfloat16((v0 - mean) * rstd * g[lane] + b[lane]);
  out[o + lane + 64]  = __float2bfloat16((v1 - mean) * rstd * g[lane + 64] + b[lane + 64]);
  out[o + lane + 128] = __float2bfloat16((v2 - mean) * rstd * g[lane + 128] + b[lane + 128]);
}

// ===== GEMM variant A: K=192, A-tile LDS-resident, serial n-tiles ===========
// out[M,N] = X[M,192](lda) @ W[N,192]^T + bias (+addin).  A staged to LDS
// ONCE per block (vector-port traffic = A bytes exactly); per n-tile: stage
// 64x192 B, 48 MFMA, epilogue.  24-slot rotation swizzle: physical col-slot
// cs of row r holds logical chunk (cs - r) mod 24 -> b128 reads <=2-way banks.
template <int EPI>
__global__ __launch_bounds__(256) void gemmA_kernel(
    const ushort* __restrict__ X, int lda, const ushort* __restrict__ W,
    const float* __restrict__ bias, const float* __restrict__ addin,
    void* __restrict__ outp, int N)
{
  __shared__ __align__(16) ushort Al[128 * 192];  // 49152 B
  __shared__ __align__(16) ushort Bl[64 * 192];   // 24576 B
  const int tid = threadIdx.x;
  const int lane = tid & 63;
  const int wv = tid >> 6;
  const int quad = lane >> 4;
  const int m15 = lane & 15;
  const long mBase = (long)blockIdx.y * 128;
  const int NT = N >> 6;

  // ---- stage A once: 3072 slots of 16B, 12 per thread ----
  #pragma unroll
  for (int r = 0; r < 12; ++r) {
    int sI = tid + r * 256;
    int row = sI / 24;
    int cs = sI - row * 24;
    int gc = cs - (row % 24); if (gc < 0) gc += 24;
    gload_lds16(X + (mBase + row) * (long)lda + gc * 8, Al + sI * 8);
  }

  const int rA0 = wv * 32 + m15, rA1 = rA0 + 16;
  const int rA0m = rA0 % 24, rA1m = rA1 % 24;

  for (int nt = 0; nt < NT; ++nt) {
    __syncthreads();   // prior n-tile's B reads done (and A/B stores drained)
    #pragma unroll
    for (int r = 0; r < 6; ++r) {       // stage B n-tile: 1536 slots
      int sI = tid + r * 256;
      int row = sI / 24;
      int cs = sI - row * 24;
      int gc = cs - (row % 24); if (gc < 0) gc += 24;
      gload_lds16(W + (long)(nt * 64 + row) * 192 + gc * 8, Bl + sI * 8);
    }
    __syncthreads();

    f32x4 acc[2][4];
    #pragma unroll
    for (int r = 0; r < 2; ++r)
      #pragma unroll
      for (int c = 0; c < 4; ++c) acc[r][c] = (f32x4){0.f, 0.f, 0.f, 0.f};

    #pragma unroll
    for (int ks = 0; ks < 6; ++ks) {
      const int l = ks * 4 + quad;
      int pa0 = l + rA0m; if (pa0 >= 24) pa0 -= 24;
      int pa1 = l + rA1m; if (pa1 >= 24) pa1 -= 24;
      bf16x8 a0 = *(const bf16x8*)&Al[rA0 * 192 + pa0 * 8];
      bf16x8 a1 = *(const bf16x8*)&Al[rA1 * 192 + pa1 * 8];
      #pragma unroll
      for (int ct = 0; ct < 4; ++ct) {
        const int rB = ct * 16 + m15;
        int pb = l + (rB % 24); if (pb >= 24) pb -= 24;
        bf16x8 b = *(const bf16x8*)&Bl[rB * 192 + pb * 8];
        acc[0][ct] = __builtin_amdgcn_mfma_f32_16x16x32_bf16(a0, b, acc[0][ct], 0, 0, 0);
        acc[1][ct] = __builtin_amdgcn_mfma_f32_16x16x32_bf16(a1, b, acc[1][ct], 0, 0, 0);
      }
    }
    // epilogue: C/D layout col=lane&15, row=(lane>>4)*4+i  [m89/m91]
    #pragma unroll
    for (int rt = 0; rt < 2; ++rt)
      #pragma unroll
      for (int ct = 0; ct < 4; ++ct)
        #pragma unroll
        for (int i = 0; i < 4; ++i) {
          long row = mBase + wv * 32 + rt * 16 + quad * 4 + i;
          int col = nt * 64 + ct * 16 + m15;
          float v = acc[rt][ct][i] + bias[col];
          if (EPI == 1) {
            v += addin[row * N + col];
            ((float*)outp)[row * N + col] = v;
          } else {
            ((__hip_bfloat16*)outp)[row * N + col] = __float2bfloat16(v);
          }
        }
  }
}

// ===== GEMM variant A+LN: proj (K=192, N=192) with residual add, f32 out, ==
// ===== and FUSED LayerNorm -> bf16 xn.  Block owns complete 128x192 rows, ==
// ===== so row stats are 12 local adds + 4 shfl_xor levels over the m15 grp ==
__global__ __launch_bounds__(256) void gemmA_ln_kernel(
    const ushort* __restrict__ X, int lda, const ushort* __restrict__ W,
    const float* __restrict__ bias, const float* __restrict__ addin,
    float* __restrict__ outp, const float* __restrict__ lng,
    const float* __restrict__ lnb, __hip_bfloat16* __restrict__ xnout)
{
  __shared__ __align__(16) ushort Al[128 * 192];
  __shared__ __align__(16) ushort Bl[64 * 192];
  const int tid = threadIdx.x;
  const int lane = tid & 63;
  const int wv = tid >> 6;
  const int quad = lane >> 4;
  const int m15 = lane & 15;
  const long mBase = (long)blockIdx.y * 128;

  #pragma unroll
  for (int r = 0; r < 12; ++r) {
    int sI = tid + r * 256;
    int row = sI / 24;
    int cs = sI - row * 24;
    int gc = cs - (row % 24); if (gc < 0) gc += 24;
    gload_lds16(X + (mBase + row) * (long)lda + gc * 8, Al + sI * 8);
  }

  const int rA0 = wv * 32 + m15, rA1 = rA0 + 16;
  const int rA0m = rA0 % 24, rA1m = rA1 % 24;

  f32x4 acc[3][2][4];
  #pragma unroll
  for (int n = 0; n < 3; ++n)
    #pragma unroll
    for (int r = 0; r < 2; ++r)
      #pragma unroll
      for (int c = 0; c < 4; ++c) acc[n][r][c] = (f32x4){0.f, 0.f, 0.f, 0.f};

  #pragma unroll
  for (int nt = 0; nt < 3; ++nt) {
    __syncthreads();
    #pragma unroll
    for (int r = 0; r < 6; ++r) {
      int sI = tid + r * 256;
      int row = sI / 24;
      int cs = sI - row * 24;
      int gc = cs - (row % 24); if (gc < 0) gc += 24;
      gload_lds16(W + (long)(nt * 64 + row) * 192 + gc * 8, Bl + sI * 8);
    }
    __syncthreads();
    #pragma unroll
    for (int ks = 0; ks < 6; ++ks) {
      const int l = ks * 4 + quad;
      int pa0 = l + rA0m; if (pa0 >= 24) pa0 -= 24;
      int pa1 = l + rA1m; if (pa1 >= 24) pa1 -= 24;
      bf16x8 a0 = *(const bf16x8*)&Al[rA0 * 192 + pa0 * 8];
      bf16x8 a1 = *(const bf16x8*)&Al[rA1 * 192 + pa1 * 8];
      #pragma unroll
      for (int ct = 0; ct < 4; ++ct) {
        const int rB = ct * 16 + m15;
        int pb = l + (rB % 24); if (pb >= 24) pb -= 24;
        bf16x8 b = *(const bf16x8*)&Bl[rB * 192 + pb * 8];
        acc[nt][0][ct] = __builtin_amdgcn_mfma_f32_16x16x32_bf16(a0, b, acc[nt][0][ct], 0, 0, 0);
        acc[nt][1][ct] = __builtin_amdgcn_mfma_f32_16x16x32_bf16(a1, b, acc[nt][1][ct], 0, 0, 0);
      }
    }
  }

  // per-col constants (12 cols per thread, shared by all 8 rows it owns)
  float cb[12], cg[12], cbb[12];
  #pragma unroll
  for (int nt = 0; nt < 3; ++nt)
    #pragma unroll
    for (int ct = 0; ct < 4; ++ct) {
      int col = nt * 64 + ct * 16 + m15;
      cb[nt * 4 + ct] = bias[col];
      cg[nt * 4 + ct] = lng[col];
      cbb[nt * 4 + ct] = lnb[col];
    }

  float sum_[2][4], sq_[2][4];
  #pragma unroll
  for (int rt = 0; rt < 2; ++rt)
    #pragma unroll
    for (int i = 0; i < 4; ++i) { sum_[rt][i] = 0.f; sq_[rt][i] = 0.f; }

  // epilogue pass 1: v = acc + bias + residual; write oc f32; keep v in regs
  #pragma unroll
  for (int nt = 0; nt < 3; ++nt)
    #pragma unroll
    for (int rt = 0; rt < 2; ++rt)
      #pragma unroll
      for (int ct = 0; ct < 4; ++ct)
        #pragma unroll
        for (int i = 0; i < 4; ++i) {
          long row = mBase + wv * 32 + rt * 16 + quad * 4 + i;
          int col = nt * 64 + ct * 16 + m15;
          float v = acc[nt][rt][ct][i] + cb[nt * 4 + ct] + addin[row * 192 + col];
          outp[row * 192 + col] = v;
          acc[nt][rt][ct][i] = v;
          sum_[rt][i] += v;
          sq_[rt][i] += v * v;
        }

  // row stats: reduce across the 16 lanes (m15) holding the same row
  float mean_[2][4], rstd_[2][4];
  #pragma unroll
  for (int rt = 0; rt < 2; ++rt)
    #pragma unroll
    for (int i = 0; i < 4; ++i) {
      float s = sum_[rt][i], q = sq_[rt][i];
      #pragma unroll
      for (int m = 1; m < 16; m <<= 1) {
        s += __shfl_xor(s, m, 64);
        q += __shfl_xor(q, m, 64);
      }
      float mean = s * (1.0f / 192.0f);
      mean_[rt][i] = mean;
      rstd_[rt][i] = rsqrtf(q * (1.0f / 192.0f) - mean * mean + 1e-5f);
    }

  // epilogue pass 2: normalized bf16 xn
  #pragma unroll
  for (int nt = 0; nt < 3; ++nt)
    #pragma unroll
    for (int rt = 0; rt < 2; ++rt)
      #pragma unroll
      for (int ct = 0; ct < 4; ++ct)
        #pragma unroll
        for (int i = 0; i < 4; ++i) {
          long row = mBase + wv * 32 + rt * 16 + quad * 4 + i;
          int col = nt * 64 + ct * 16 + m15;
          float v = (acc[nt][rt][ct][i] - mean_[rt][i]) * rstd_[rt][i] *
                        cg[nt * 4 + ct] + cbb[nt * 4 + ct];
          xnout[row * 192 + col] = __float2bfloat16(v);
        }
}

// ===== GEMM variant B: fc2 (K=768, N=192). 4 K-chunks, 3 live n-tile accs ==
__global__ __launch_bounds__(256) void gemmB_kernel(
    const ushort* __restrict__ X, const ushort* __restrict__ W,
    const float* __restrict__ bias, const float* __restrict__ addin,
    float* __restrict__ outp)
{
  __shared__ __align__(16) ushort Al[128 * 192];
  __shared__ __align__(16) ushort Bl[64 * 192];
  const int tid = threadIdx.x;
  const int lane = tid & 63;
  const int wv = tid >> 6;
  const int quad = lane >> 4;
  const int m15 = lane & 15;
  const long mBase = (long)blockIdx.y * 128;

  const int rA0 = wv * 32 + m15, rA1 = rA0 + 16;
  const int rA0m = rA0 % 24, rA1m = rA1 % 24;

  f32x4 acc[3][2][4];
  #pragma unroll
  for (int n = 0; n < 3; ++n)
    #pragma unroll
    for (int r = 0; r < 2; ++r)
      #pragma unroll
      for (int c = 0; c < 4; ++c) acc[n][r][c] = (f32x4){0.f, 0.f, 0.f, 0.f};

  for (int kc = 0; kc < 4; ++kc) {
    for (int nt = 0; nt < 3; ++nt) {
      __syncthreads();
      if (nt == 0) {
        #pragma unroll
        for (int r = 0; r < 12; ++r) {     // stage A chunk
          int sI = tid + r * 256;
          int row = sI / 24;
          int cs = sI - row * 24;
          int gc = cs - (row % 24); if (gc < 0) gc += 24;
          gload_lds16(X + (mBase + row) * 768l + kc * 192 + gc * 8, Al + sI * 8);
        }
      }
      #pragma unroll
      for (int r = 0; r < 6; ++r) {        // stage B tile for (nt, kc)
        int sI = tid + r * 256;
        int row = sI / 24;
        int cs = sI - row * 24;
        int gc = cs - (row % 24); if (gc < 0) gc += 24;
        gload_lds16(W + (long)(nt * 64 + row) * 768 + kc * 192 + gc * 8, Bl + sI * 8);
      }
      __syncthreads();
      #pragma unroll
      for (int ks = 0; ks < 6; ++ks) {
        const int l = ks * 4 + quad;
        int pa0 = l + rA0m; if (pa0 >= 24) pa0 -= 24;
        int pa1 = l + rA1m; if (pa1 >= 24) pa1 -= 24;
        bf16x8 a0 = *(const bf16x8*)&Al[rA0 * 192 + pa0 * 8];
        bf16x8 a1 = *(const bf16x8*)&Al[rA1 * 192 + pa1 * 8];
        #pragma unroll
        for (int ct = 0; ct < 4; ++ct) {
          const int rB = ct * 16 + m15;
          int pb = l + (rB % 24); if (pb >= 24) pb -= 24;
          bf16x8 b = *(const bf16x8*)&Bl[rB * 192 + pb * 8];
          acc[nt][0][ct] = __builtin_amdgcn_mfma_f32_16x16x32_bf16(a0, b, acc[nt][0][ct], 0, 0, 0);
          acc[nt][1][ct] = __builtin_amdgcn_mfma_f32_16x16x32_bf16(a1, b, acc[nt][1][ct], 0, 0, 0);
        }
      }
    }
  }
  #pragma unroll
  for (int nt = 0; nt < 3; ++nt)
    #pragma unroll
    for (int rt = 0; rt < 2; ++rt)
      #pragma unroll
      for (int ct = 0; ct < 4; ++ct)
        #pragma unroll
        for (int i = 0; i < 4; ++i) {
          long row = mBase + wv * 32 + rt * 16 + quad * 4 + i;
          int col = nt * 64 + ct * 16 + m15;
          float v = acc[nt][rt][ct][i] + bias[col] + addin[row * 192 + col];
          outp[row * 192 + col] = v;
        }
}

// -------- window attention: ONE WAVE PER WINDOW-HEAD, barrier-free ----------
// VALU-bound (MfmaUtil 0, VALUBusy 60%): dot/accum done in f32x2 so the
// compiler emits full-rate v_pk_fma_f32 (halves FMA issue slots); max/sum
// use 4-way accumulators to cut the 48-deep serial dependency chains.
__global__ __launch_bounds__(256) void attn_kernel(
    const float* __restrict__ rpe, __hip_bfloat16* __restrict__ qkv)
{
  __shared__ float lds[4 * 2352 + 4 * 172];
  const int tid = threadIdx.x;
  const int lane = tid & 63;
  const int wv = tid >> 6;
  const int wh = blockIdx.x * 4 + wv;
  const int h = wh & 7;
  const int win = wh >> 3;
  const int b = win >> 8;
  const int wl = win & 255;
  const int whi = wl >> 4;
  const int wwi = wl & 15;
  ushort* qkv_u = (ushort*)qkv;
  float* kv_w = &lds[wv * 2352];
  float* bias_w = &lds[4 * 2352 + wv * 172];

  const long rowbase = (long)b * 12544 + (long)(whi * 7) * 112 + wwi * 7;

  #pragma unroll
  for (int rnd = 0; rnd < 10; ++rnd) {
    int e = lane + rnd * 64;
    if (e < 588) {
      int t = e / 12;
      int r = e - t * 12;
      int mat = r / 6;
      int d4 = (r - mat * 6) * 4;
      int py = t / 7, px = t - py * 7;
      long row = rowbase + py * 112 + px;
      ushort4 u = *(const ushort4*)(qkv_u + row * 576 + 192 + mat * 192 + h * 24 + d4);
      float* dst = kv_w + mat * 1176 + t * 24 + d4;
      dst[0] = bfu2f(u.x); dst[1] = bfu2f(u.y);
      dst[2] = bfu2f(u.z); dst[3] = bfu2f(u.w);
    }
  }
  for (int r = lane; r < 169; r += 64) bias_w[r] = rpe[r * 8 + h];
  __syncthreads();

  const int i = (lane < 49) ? lane : 48;
  const int yi = i / 7, xi = i - yi * 7;
  const int base_i = yi * 13 + xi + 84;
  const long myrow = rowbase + yi * 112 + xi;

  f32x2 q2[12];
  #pragma unroll
  for (int d4 = 0; d4 < 24; d4 += 4) {
    ushort4 u = *(const ushort4*)(qkv_u + myrow * 576 + h * 24 + d4);
    q2[(d4 >> 1)]     = (f32x2){bfu2f(u.x), bfu2f(u.y)};
    q2[(d4 >> 1) + 1] = (f32x2){bfu2f(u.z), bfu2f(u.w)};
  }

  float s[49];
  #pragma unroll
  for (int j = 0; j < 49; ++j) {
    const int yj = j / 7, xj = j % 7;
    const int base_j = yj * 13 + xj;
    const float* kr = kv_w + j * 24;
    f32x2 a2 = {0.f, 0.f};
    #pragma unroll
    for (int d4 = 0; d4 < 24; d4 += 4) {
      f32x4 kk = *(const f32x4*)(kr + d4);
      f32x2 klo = __builtin_shufflevector(kk, kk, 0, 1);
      f32x2 khi = __builtin_shufflevector(kk, kk, 2, 3);
      a2 += q2[(d4 >> 1)] * klo;
      a2 += q2[(d4 >> 1) + 1] * khi;
    }
    s[j] = a2[0] + a2[1] + bias_w[base_i - base_j];
  }

  // max: 4-way accumulators (exact under reassociation)
  float m0 = fmaxf(s[0], s[48]);
  float m1 = s[1], m2 = s[2], m3 = s[3];
  #pragma unroll
  for (int j = 4; j < 48; j += 4) {
    m0 = fmaxf(m0, s[j]);     m1 = fmaxf(m1, s[j + 1]);
    m2 = fmaxf(m2, s[j + 2]); m3 = fmaxf(m3, s[j + 3]);
  }
  const float mx = fmaxf(fmaxf(m0, m1), fmaxf(m2, m3));

  #pragma unroll
  for (int j = 0; j < 49; ++j) s[j] = __expf(s[j] - mx);

  float t0 = s[48], t1 = 0.f, t2 = 0.f, t3 = 0.f;
  #pragma unroll
  for (int j = 0; j < 48; j += 4) {
    t0 += s[j]; t1 += s[j + 1]; t2 += s[j + 2]; t3 += s[j + 3];
  }
  const float inv = 1.f / ((t0 + t1) + (t2 + t3));
  #pragma unroll
  for (int j = 0; j < 49; ++j) s[j] *= inv;

  f32x2 o2[12];
  #pragma unroll
  for (int dd = 0; dd < 12; ++dd) o2[dd] = (f32x2){0.f, 0.f};
  #pragma unroll
  for (int j = 0; j < 49; ++j) {
    const f32x2 p2 = {s[j], s[j]};
    const float* vr = kv_w + 1176 + j * 24;
    #pragma unroll
    for (int d4 = 0; d4 < 24; d4 += 4) {
      f32x4 vv = *(const f32x4*)(vr + d4);
      o2[(d4 >> 1)]     += p2 * __builtin_shufflevector(vv, vv, 0, 1);
      o2[(d4 >> 1) + 1] += p2 * __builtin_shufflevector(vv, vv, 2, 3);
    }
  }

  if (lane < 49) {
    #pragma unroll
    for (int d4 = 0; d4 < 24; d4 += 4) {
      ushort4 u;
      u.x = f2bfu(o2[(d4 >> 1)][0]);     u.y = f2bfu(o2[(d4 >> 1)][1]);
      u.z = f2bfu(o2[(d4 >> 1) + 1][0]); u.w = f2bfu(o2[(d4 >> 1) + 1][1]);
      *(ushort4*)(qkv_u + myrow * 576 + h * 24 + d4) = u;
    }
  }
}

// -------- depthwise 3x3 conv + bias + tanh-GELU, w-slide x2 -----------------
__global__ __launch_bounds__(192) void dwconv_gelu_kernel(
    const ushort* __restrict__ y1, const float* __restrict__ w,
    const float* __restrict__ bias, ushort* __restrict__ y2)
{
  const int c = threadIdx.x * 4;       // channel group
  const int w0 = blockIdx.y * 2;       // output cols w0, w0+1
  const int b = blockIdx.z;
  const int h0 = blockIdx.x * 28;

  float wt[9][4];
  #pragma unroll
  for (int k = 0; k < 9; ++k)
    #pragma unroll
    for (int j = 0; j < 4; ++j) wt[k][j] = w[(c + j) * 9 + k];
  float bs[4];
  #pragma unroll
  for (int j = 0; j < 4; ++j) bs[j] = bias[c + j];

  const bool okL = (w0 > 0), okR = (w0 + 2 < 112);
  ushort4 rb[6][4];   // rows (ring), cols w0-1..w0+2, packed bf16x4

  auto loadrow = [&](int h, ushort4 dst[4]) {
    const ushort4 z = {0, 0, 0, 0};
    if (h < 0 || h >= 112) {
      dst[0] = z; dst[1] = z; dst[2] = z; dst[3] = z;
      return;
    }
    const ushort* p = y1 + (((size_t)(b * 112 + h)) * 112 + w0) * HID + c;
    dst[0] = okL ? *(const ushort4*)(p - HID) : z;
    dst[1] = *(const ushort4*)(p);
    dst[2] = *(const ushort4*)(p + HID);
    dst[3] = okR ? *(const ushort4*)(p + 2 * HID) : z;
  };

  loadrow(h0 - 1, rb[0]);
  loadrow(h0, rb[1]);

  for (int m = 0; m < 7; ++m) {
    const int hb = h0 + m * 4;
    loadrow(hb + 1, rb[2]);
    loadrow(hb + 2, rb[3]);
    loadrow(hb + 3, rb[4]);
    loadrow(hb + 4, rb[5]);
    #pragma unroll
    for (int o = 0; o < 4; ++o) {
      float acc0[4], acc1[4];
      #pragma unroll
      for (int j = 0; j < 4; ++j) { acc0[j] = bs[j]; acc1[j] = bs[j]; }
      #pragma unroll
      for (int dy = 0; dy < 3; ++dy) {
        float col[4][4];
        #pragma unroll
        for (int x = 0; x < 4; ++x) {
          ushort4 u = rb[o + dy][x];
          col[x][0] = bfu2f(u.x); col[x][1] = bfu2f(u.y);
          col[x][2] = bfu2f(u.z); col[x][3] = bfu2f(u.w);
        }
        #pragma unroll
        for (int dx = 0; dx < 3; ++dx)
          #pragma unroll
          for (int j = 0; j < 4; ++j) {
            acc0[j] += wt[dy * 3 + dx][j] * col[dx][j];
            acc1[j] += wt[dy * 3 + dx][j] * col[dx + 1][j];
          }
      }
      ushort* outp = y2 + (((size_t)(b * 112 + hb + o)) * 112 + w0) * HID + c;
      ushort4 o0, o1;
      o0.x = f2bfu(fgelu(acc0[0])); o0.y = f2bfu(fgelu(acc0[1]));
      o0.z = f2bfu(fgelu(acc0[2])); o0.w = f2bfu(fgelu(acc0[3]));
      o1.x = f2bfu(fgelu(acc1[0])); o1.y = f2bfu(fgelu(acc1[1]));
      o1.z = f2bfu(fgelu(acc1[2])); o1.w = f2bfu(fgelu(acc1[3]));
      *(ushort4*)(outp) = o0;
      *(ushort4*)(outp + HID) = o1;
    }
    #pragma unroll
    for (int x = 0; x < 4; ++x) {
      rb[0][x] = rb[4][x];
      rb[1][x] = rb[5][x];
    }
  }
}

// ---------------------------------------------------------------------------
extern "C" void kernel_launch(void* const* d_in, const int* in_sizes, int n_in,
                              void* d_out, int out_size, void* d_ws, size_t ws_size,
                              hipStream_t stream) {
  const float* x      = (const float*)d_in[0];
  const float* n1g    = (const float*)d_in[1];
  const float* n1b    = (const float*)d_in[2];
  const float* q_w    = (const float*)d_in[3];
  const float* q_b    = (const float*)d_in[4];
  const float* kv_w   = (const float*)d_in[5];
  const float* kv_b   = (const float*)d_in[6];
  const float* rpe    = (const float*)d_in[7];
  const float* proj_w = (const float*)d_in[8];
  const float* proj_b = (const float*)d_in[9];
  const float* n2g    = (const float*)d_in[10];
  const float* n2b    = (const float*)d_in[11];
  const float* fc1_w  = (const float*)d_in[12];
  const float* fc1_b  = (const float*)d_in[13];
  const float* dw_w   = (const float*)d_in[14];
  const float* dw_b   = (const float*)d_in[15];
  const float* fc2_w  = (const float*)d_in[16];
  const float* fc2_b  = (const float*)d_in[17];
  float* out = (float*)d_out;

  // ---- weights at front of ws (~0.9 MB) ----
  char* ws = (char*)d_ws;
  __hip_bfloat16* wcat  = (__hip_bfloat16*)(ws);               // 576*192 bf16
  __hip_bfloat16* projw = (__hip_bfloat16*)(ws + 221184);      // 192*192
  __hip_bfloat16* fc1w  = (__hip_bfloat16*)(ws + 294912);      // 768*192
  __hip_bfloat16* fc2w  = (__hip_bfloat16*)(ws + 589824);      // 192*768
  float* bcat           = (float*)(ws + 884736);               // 576 f32
  const size_t WOFF = 1u << 20;                                // 1 MB

  // ---- pick images-per-chunk CB so the activation buffers fit ws_size ----
  int CB = 8;
  while (CB > 1 && WOFF + (size_t)CB * 12544 * 3456 > ws_size) CB >>= 1;
  const size_t Mc = (size_t)CB * 12544;
  char* Abuf = ws + WOFF;                        // xn / yn   (bf16 Mc x 192)
  char* Bbuf = Abuf + Mc * 384;                  // qkv (Mc x 576) / y2 (Mc x 768)
  char* Cbuf = Bbuf + Mc * 1536;                 // y1 (bf16 Mc x 768)
  __hip_bfloat16* xn  = (__hip_bfloat16*)Abuf;
  __hip_bfloat16* qkv = (__hip_bfloat16*)Bbuf;
  __hip_bfloat16* y2  = (__hip_bfloat16*)Bbuf;
  __hip_bfloat16* y1  = (__hip_bfloat16*)Cbuf;

  prep_kernel<<<576, 256, 0, stream>>>(q_w, q_b, kv_w, kv_b, proj_w, fc1_w,
                                       fc2_w, wcat, bcat, projw, fc1w, fc2w);

  const int nChunks = 8 / CB;
  const int mt = CB * 98;
  for (int cchunk = 0; cchunk < nChunks; ++cchunk) {
    const size_t toff = (size_t)cchunk * Mc;
    const float* xc = x + toff * C_DIM;
    float* oc = out + toff * C_DIM;

    ln_kernel<<<(int)(Mc / 4), 256, 0, stream>>>(xc, n1g, n1b, xn);
    gemmA_kernel<0><<<dim3(1, mt), 256, 0, stream>>>(
        (const ushort*)xn, 192, (const ushort*)wcat, bcat, nullptr, qkv, 576);
    attn_kernel<<<CB * 512, 256, 0, stream>>>(rpe, qkv);
    gemmA_ln_kernel<<<dim3(1, mt), 256, 0, stream>>>(
        (const ushort*)qkv, 576, (const ushort*)projw, proj_b, xc, oc,
        n2g, n2b, xn);
    gemmA_kernel<0><<<dim3(1, mt), 256, 0, stream>>>(
        (const ushort*)xn, 192, (const ushort*)fc1w, fc1_b, nullptr, y1, 768);
    dwconv_gelu_kernel<<<dim3(4, 56, CB), 192, 0, stream>>>(
        (const ushort*)y1, dw_w, dw_b, (ushort*)y2);
    gemmB_kernel<<<dim3(1, mt), 256, 0, stream>>>(
        (const ushort*)y2, (const ushort*)fc2w, fc2_b, oc, oc);
  }
}

// Round 2
// 629.244 us; speedup vs baseline: 1.3072x; 1.3072x over previous
//
#include <hip/hip_runtime.h>
#include <hip/hip_bf16.h>
#include <cmath>

// Problem constants (B=8, H=W=112, C=192, heads=8, hd=24, ps=7, hid=768)
#define C_DIM 192
#define HID 768

typedef __attribute__((ext_vector_type(8))) __bf16 bf16x8;
typedef __attribute__((ext_vector_type(4))) float f32x4;
typedef __attribute__((ext_vector_type(2))) float f32x2;

__device__ __forceinline__ void gload_lds16(const void* g, void* l) {
  __builtin_amdgcn_global_load_lds(
      (__attribute__((address_space(1))) void*)(const_cast<void*>(g)),
      (__attribute__((address_space(3))) void*)(l), 16, 0, 0);
}

__device__ __forceinline__ float bfu2f(ushort u) {
  return __uint_as_float((unsigned)u << 16);
}
__device__ __forceinline__ ushort f2bfu(float f) {
  __hip_bfloat16 h = __float2bfloat16(f);
  return *reinterpret_cast<ushort*>(&h);
}
// tanh-form GELU: |err| ~3e-4 << bf16 ulp (validated R5, absmax 0.0156)
__device__ __forceinline__ float fgelu(float x) {
  float z = x * (1.5957691216f + 0.071354816f * x * x);
  return x / (1.f + __expf(-z));
}

// ---------------- prep: weights fp32 -> bf16 (+ fold q scale) ----------------
__global__ __launch_bounds__(256) void prep_kernel(
    const float* __restrict__ q_w, const float* __restrict__ q_b,
    const float* __restrict__ kv_w, const float* __restrict__ kv_b,
    const float* __restrict__ proj_w, const float* __restrict__ fc1_w,
    const float* __restrict__ fc2_w,
    __hip_bfloat16* __restrict__ wcat, float* __restrict__ bcat,
    __hip_bfloat16* __restrict__ projw, __hip_bfloat16* __restrict__ fc1w,
    __hip_bfloat16* __restrict__ fc2w)
{
  int idx = blockIdx.x * 256 + threadIdx.x;
  const float scale = 0.20412414523193154f;  // 24^-0.5
  if (idx < 110592) {
    float v = (idx < 36864) ? q_w[idx] * scale : kv_w[idx - 36864];
    wcat[idx] = __float2bfloat16(v);
  }
  if (idx < 576) bcat[idx] = (idx < 192) ? q_b[idx] * scale : kv_b[idx - 192];
  if (idx < 36864) projw[idx] = __float2bfloat16(proj_w[idx]);
  if (idx < 147456) {
    fc1w[idx] = __float2bfloat16(fc1_w[idx]);
    fc2w[idx] = __float2bfloat16(fc2_w[idx]);
  }
}

// -------- LayerNorm fp32 -> bf16, one wave per token (192 = 64*3) -----------
__global__ __launch_bounds__(256) void ln_kernel(
    const float* __restrict__ x, const float* __restrict__ g,
    const float* __restrict__ b, __hip_bfloat16* __restrict__ out)
{
  int t = blockIdx.x * 4 + (threadIdx.x >> 6);
  int lane = threadIdx.x & 63;
  const float* xr = x + (size_t)t * C_DIM;
  float v0 = xr[lane], v1 = xr[lane + 64], v2 = xr[lane + 128];
  float s = v0 + v1 + v2;
  float sq = v0 * v0 + v1 * v1 + v2 * v2;
  #pragma unroll
  for (int off = 32; off > 0; off >>= 1) {
    s += __shfl_xor(s, off, 64);
    sq += __shfl_xor(sq, off, 64);
  }
  float mean = s * (1.0f / 192.0f);
  float var = sq * (1.0f / 192.0f) - mean * mean;
  float rstd = rsqrtf(var + 1e-5f);
  size_t o = (size_t)t * C_DIM;
  out[o + lane]       = __float2bfloat16((v0 - mean) * rstd * g[lane] + b[lane]);
  out[o + lane + 64]  = __float2bfloat16((v1 - mean) * rstd * g[lane + 64] + b[lane + 64]);
  out[o + lane + 128] = __float2bfloat16((v2 - mean) * rstd * g[lane + 128] + b[lane + 128]);
}

// ===== GEMM variant A: K=192, A-tile LDS-resident, serial n-tiles ===========
// out[M,N] = X[M,192](lda) @ W[N,192]^T + bias (+addin).  A staged to LDS
// ONCE per block; per n-tile: stage 64x192 B, MFMA, epilogue.  24-slot
// rotation swizzle: physical col-slot cs of row r holds logical chunk
// (cs - r) mod 24 -> b128 reads <=2-way banks.
// 512 thr / 8 waves, 1x16-row tile per wave: 2 blocks/CU -> 4 waves/SIMD
// (was 2/SIMD at 256 thr; counters showed occupancy 13%, latency-bound).
template <int EPI>
__global__ __launch_bounds__(512, 4) void gemmA_kernel(
    const ushort* __restrict__ X, int lda, const ushort* __restrict__ W,
    const float* __restrict__ bias, const float* __restrict__ addin,
    void* __restrict__ outp, int N)
{
  __shared__ __align__(16) ushort Al[128 * 192];  // 49152 B
  __shared__ __align__(16) ushort Bl[64 * 192];   // 24576 B
  const int tid = threadIdx.x;
  const int wv = tid >> 6;          // 0..7
  const int lane = tid & 63;
  const int quad = lane >> 4;
  const int m15 = lane & 15;
  const long mBase = (long)blockIdx.y * 128;
  const int NT = N >> 6;

  // ---- stage A once: 3072 slots of 16B, 6 per thread ----
  #pragma unroll
  for (int r = 0; r < 6; ++r) {
    int sI = tid + r * 512;
    int row = sI / 24;
    int cs = sI - row * 24;
    int gc = cs - (row % 24); if (gc < 0) gc += 24;
    gload_lds16(X + (mBase + row) * (long)lda + gc * 8, Al + sI * 8);
  }

  const int rA0 = wv * 16 + m15;
  const int rA0m = rA0 % 24;

  for (int nt = 0; nt < NT; ++nt) {
    __syncthreads();   // prior n-tile's B reads done (and A/B stores drained)
    #pragma unroll
    for (int r = 0; r < 3; ++r) {       // stage B n-tile: 1536 slots
      int sI = tid + r * 512;
      int row = sI / 24;
      int cs = sI - row * 24;
      int gc = cs - (row % 24); if (gc < 0) gc += 24;
      gload_lds16(W + (long)(nt * 64 + row) * 192 + gc * 8, Bl + sI * 8);
    }
    __syncthreads();

    f32x4 acc[4];
    #pragma unroll
    for (int c = 0; c < 4; ++c) acc[c] = (f32x4){0.f, 0.f, 0.f, 0.f};

    #pragma unroll
    for (int ks = 0; ks < 6; ++ks) {
      const int l = ks * 4 + quad;
      int pa0 = l + rA0m; if (pa0 >= 24) pa0 -= 24;
      bf16x8 a0 = *(const bf16x8*)&Al[rA0 * 192 + pa0 * 8];
      #pragma unroll
      for (int ct = 0; ct < 4; ++ct) {
        const int rB = ct * 16 + m15;
        int pb = l + (rB % 24); if (pb >= 24) pb -= 24;
        bf16x8 b = *(const bf16x8*)&Bl[rB * 192 + pb * 8];
        acc[ct] = __builtin_amdgcn_mfma_f32_16x16x32_bf16(a0, b, acc[ct], 0, 0, 0);
      }
    }
    // epilogue: C/D layout col=lane&15, row=(lane>>4)*4+i  [m89/m91]
    #pragma unroll
    for (int ct = 0; ct < 4; ++ct)
      #pragma unroll
      for (int i = 0; i < 4; ++i) {
        long row = mBase + wv * 16 + quad * 4 + i;
        int col = nt * 64 + ct * 16 + m15;
        float v = acc[ct][i] + bias[col];
        if (EPI == 1) {
          v += addin[row * N + col];
          ((float*)outp)[row * N + col] = v;
        } else {
          ((__hip_bfloat16*)outp)[row * N + col] = __float2bfloat16(v);
        }
      }
  }
}

// ===== GEMM variant A+LN: proj (K=192, N=192) with residual add, f32 out, ==
// ===== and FUSED LayerNorm -> bf16 xn.  Block owns complete 128x192 rows, ==
// ===== so row stats are local adds + 4 shfl_xor levels over the m15 group ==
__global__ __launch_bounds__(512, 4) void gemmA_ln_kernel(
    const ushort* __restrict__ X, int lda, const ushort* __restrict__ W,
    const float* __restrict__ bias, const float* __restrict__ addin,
    float* __restrict__ outp, const float* __restrict__ lng,
    const float* __restrict__ lnb, __hip_bfloat16* __restrict__ xnout)
{
  __shared__ __align__(16) ushort Al[128 * 192];
  __shared__ __align__(16) ushort Bl[64 * 192];
  const int tid = threadIdx.x;
  const int wv = tid >> 6;
  const int lane = tid & 63;
  const int quad = lane >> 4;
  const int m15 = lane & 15;
  const long mBase = (long)blockIdx.y * 128;

  #pragma unroll
  for (int r = 0; r < 6; ++r) {
    int sI = tid + r * 512;
    int row = sI / 24;
    int cs = sI - row * 24;
    int gc = cs - (row % 24); if (gc < 0) gc += 24;
    gload_lds16(X + (mBase + row) * (long)lda + gc * 8, Al + sI * 8);
  }

  const int rA0 = wv * 16 + m15;
  const int rA0m = rA0 % 24;

  f32x4 acc[3][4];
  #pragma unroll
  for (int n = 0; n < 3; ++n)
    #pragma unroll
    for (int c = 0; c < 4; ++c) acc[n][c] = (f32x4){0.f, 0.f, 0.f, 0.f};

  #pragma unroll
  for (int nt = 0; nt < 3; ++nt) {
    __syncthreads();
    #pragma unroll
    for (int r = 0; r < 3; ++r) {
      int sI = tid + r * 512;
      int row = sI / 24;
      int cs = sI - row * 24;
      int gc = cs - (row % 24); if (gc < 0) gc += 24;
      gload_lds16(W + (long)(nt * 64 + row) * 192 + gc * 8, Bl + sI * 8);
    }
    __syncthreads();
    #pragma unroll
    for (int ks = 0; ks < 6; ++ks) {
      const int l = ks * 4 + quad;
      int pa0 = l + rA0m; if (pa0 >= 24) pa0 -= 24;
      bf16x8 a0 = *(const bf16x8*)&Al[rA0 * 192 + pa0 * 8];
      #pragma unroll
      for (int ct = 0; ct < 4; ++ct) {
        const int rB = ct * 16 + m15;
        int pb = l + (rB % 24); if (pb >= 24) pb -= 24;
        bf16x8 b = *(const bf16x8*)&Bl[rB * 192 + pb * 8];
        acc[nt][ct] = __builtin_amdgcn_mfma_f32_16x16x32_bf16(a0, b, acc[nt][ct], 0, 0, 0);
      }
    }
  }

  float sum_[4], sq_[4];
  #pragma unroll
  for (int i = 0; i < 4; ++i) { sum_[i] = 0.f; sq_[i] = 0.f; }

  // epilogue pass 1: v = acc + bias + residual; write oc f32; keep v in regs
  #pragma unroll
  for (int nt = 0; nt < 3; ++nt)
    #pragma unroll
    for (int ct = 0; ct < 4; ++ct) {
      int col = nt * 64 + ct * 16 + m15;
      float cb = bias[col];
      #pragma unroll
      for (int i = 0; i < 4; ++i) {
        long row = mBase + wv * 16 + quad * 4 + i;
        float v = acc[nt][ct][i] + cb + addin[row * 192 + col];
        outp[row * 192 + col] = v;
        acc[nt][ct][i] = v;
        sum_[i] += v;
        sq_[i] += v * v;
      }
    }

  // row stats: reduce across the 16 lanes (m15) holding the same row
  float mean_[4], rstd_[4];
  #pragma unroll
  for (int i = 0; i < 4; ++i) {
    float s = sum_[i], q = sq_[i];
    #pragma unroll
    for (int m = 1; m < 16; m <<= 1) {
      s += __shfl_xor(s, m, 64);
      q += __shfl_xor(q, m, 64);
    }
    float mean = s * (1.0f / 192.0f);
    mean_[i] = mean;
    rstd_[i] = rsqrtf(q * (1.0f / 192.0f) - mean * mean + 1e-5f);
  }

  // epilogue pass 2: normalized bf16 xn
  #pragma unroll
  for (int nt = 0; nt < 3; ++nt)
    #pragma unroll
    for (int ct = 0; ct < 4; ++ct) {
      int col = nt * 64 + ct * 16 + m15;
      float cg = lng[col], cbb = lnb[col];
      #pragma unroll
      for (int i = 0; i < 4; ++i) {
        long row = mBase + wv * 16 + quad * 4 + i;
        float v = (acc[nt][ct][i] - mean_[i]) * rstd_[i] * cg + cbb;
        xnout[row * 192 + col] = __float2bfloat16(v);
      }
    }
}

// ===== GEMM variant B: fc2 (K=768, N=192). 4 K-chunks, 3 live n-tile accs ==
__global__ __launch_bounds__(512, 4) void gemmB_kernel(
    const ushort* __restrict__ X, const ushort* __restrict__ W,
    const float* __restrict__ bias, const float* __restrict__ addin,
    float* __restrict__ outp)
{
  __shared__ __align__(16) ushort Al[128 * 192];
  __shared__ __align__(16) ushort Bl[64 * 192];
  const int tid = threadIdx.x;
  const int wv = tid >> 6;
  const int lane = tid & 63;
  const int quad = lane >> 4;
  const int m15 = lane & 15;
  const long mBase = (long)blockIdx.y * 128;

  const int rA0 = wv * 16 + m15;
  const int rA0m = rA0 % 24;

  f32x4 acc[3][4];
  #pragma unroll
  for (int n = 0; n < 3; ++n)
    #pragma unroll
    for (int c = 0; c < 4; ++c) acc[n][c] = (f32x4){0.f, 0.f, 0.f, 0.f};

  for (int kc = 0; kc < 4; ++kc) {
    for (int nt = 0; nt < 3; ++nt) {
      __syncthreads();
      if (nt == 0) {
        #pragma unroll
        for (int r = 0; r < 6; ++r) {     // stage A chunk
          int sI = tid + r * 512;
          int row = sI / 24;
          int cs = sI - row * 24;
          int gc = cs - (row % 24); if (gc < 0) gc += 24;
          gload_lds16(X + (mBase + row) * 768l + kc * 192 + gc * 8, Al + sI * 8);
        }
      }
      #pragma unroll
      for (int r = 0; r < 3; ++r) {        // stage B tile for (nt, kc)
        int sI = tid + r * 512;
        int row = sI / 24;
        int cs = sI - row * 24;
        int gc = cs - (row % 24); if (gc < 0) gc += 24;
        gload_lds16(W + (long)(nt * 64 + row) * 768 + kc * 192 + gc * 8, Bl + sI * 8);
      }
      __syncthreads();
      #pragma unroll
      for (int ks = 0; ks < 6; ++ks) {
        const int l = ks * 4 + quad;
        int pa0 = l + rA0m; if (pa0 >= 24) pa0 -= 24;
        bf16x8 a0 = *(const bf16x8*)&Al[rA0 * 192 + pa0 * 8];
        #pragma unroll
        for (int ct = 0; ct < 4; ++ct) {
          const int rB = ct * 16 + m15;
          int pb = l + (rB % 24); if (pb >= 24) pb -= 24;
          bf16x8 b = *(const bf16x8*)&Bl[rB * 192 + pb * 8];
          acc[nt][ct] = __builtin_amdgcn_mfma_f32_16x16x32_bf16(a0, b, acc[nt][ct], 0, 0, 0);
        }
      }
    }
  }
  #pragma unroll
  for (int nt = 0; nt < 3; ++nt)
    #pragma unroll
    for (int ct = 0; ct < 4; ++ct)
      #pragma unroll
      for (int i = 0; i < 4; ++i) {
        long row = mBase + wv * 16 + quad * 4 + i;
        int col = nt * 64 + ct * 16 + m15;
        float v = acc[nt][ct][i] + bias[col] + addin[row * 192 + col];
        outp[row * 192 + col] = v;
      }
}

// -------- window attention: ONE WAVE PER WINDOW-HEAD, barrier-free ----------
// VALU-bound (MfmaUtil 0): dot/accum done in f32x2 so the compiler emits
// full-rate v_pk_fma_f32 (halves FMA issue slots); max/sum use 4-way
// accumulators to cut the 48-deep serial dependency chains.
__global__ __launch_bounds__(256) void attn_kernel(
    const float* __restrict__ rpe, __hip_bfloat16* __restrict__ qkv)
{
  __shared__ float lds[4 * 2352 + 4 * 172];
  const int tid = threadIdx.x;
  const int lane = tid & 63;
  const int wv = tid >> 6;
  const int wh = blockIdx.x * 4 + wv;
  const int h = wh & 7;
  const int win = wh >> 3;
  const int b = win >> 8;
  const int wl = win & 255;
  const int whi = wl >> 4;
  const int wwi = wl & 15;
  ushort* qkv_u = (ushort*)qkv;
  float* kv_w = &lds[wv * 2352];
  float* bias_w = &lds[4 * 2352 + wv * 172];

  const long rowbase = (long)b * 12544 + (long)(whi * 7) * 112 + wwi * 7;

  #pragma unroll
  for (int rnd = 0; rnd < 10; ++rnd) {
    int e = lane + rnd * 64;
    if (e < 588) {
      int t = e / 12;
      int r = e - t * 12;
      int mat = r / 6;
      int d4 = (r - mat * 6) * 4;
      int py = t / 7, px = t - py * 7;
      long row = rowbase + py * 112 + px;
      ushort4 u = *(const ushort4*)(qkv_u + row * 576 + 192 + mat * 192 + h * 24 + d4);
      float* dst = kv_w + mat * 1176 + t * 24 + d4;
      dst[0] = bfu2f(u.x); dst[1] = bfu2f(u.y);
      dst[2] = bfu2f(u.z); dst[3] = bfu2f(u.w);
    }
  }
  for (int r = lane; r < 169; r += 64) bias_w[r] = rpe[r * 8 + h];
  __syncthreads();

  const int i = (lane < 49) ? lane : 48;
  const int yi = i / 7, xi = i - yi * 7;
  const int base_i = yi * 13 + xi + 84;
  const long myrow = rowbase + yi * 112 + xi;

  f32x2 q2[12];
  #pragma unroll
  for (int d4 = 0; d4 < 24; d4 += 4) {
    ushort4 u = *(const ushort4*)(qkv_u + myrow * 576 + h * 24 + d4);
    q2[(d4 >> 1)]     = (f32x2){bfu2f(u.x), bfu2f(u.y)};
    q2[(d4 >> 1) + 1] = (f32x2){bfu2f(u.z), bfu2f(u.w)};
  }

  float s[49];
  #pragma unroll
  for (int j = 0; j < 49; ++j) {
    const int yj = j / 7, xj = j % 7;
    const int base_j = yj * 13 + xj;
    const float* kr = kv_w + j * 24;
    f32x2 a2 = {0.f, 0.f};
    #pragma unroll
    for (int d4 = 0; d4 < 24; d4 += 4) {
      f32x4 kk = *(const f32x4*)(kr + d4);
      f32x2 klo = __builtin_shufflevector(kk, kk, 0, 1);
      f32x2 khi = __builtin_shufflevector(kk, kk, 2, 3);
      a2 += q2[(d4 >> 1)] * klo;
      a2 += q2[(d4 >> 1) + 1] * khi;
    }
    s[j] = a2[0] + a2[1] + bias_w[base_i - base_j];
  }

  // max: 4-way accumulators (exact under reassociation)
  float m0 = fmaxf(s[0], s[48]);
  float m1 = s[1], m2 = s[2], m3 = s[3];
  #pragma unroll
  for (int j = 4; j < 48; j += 4) {
    m0 = fmaxf(m0, s[j]);     m1 = fmaxf(m1, s[j + 1]);
    m2 = fmaxf(m2, s[j + 2]); m3 = fmaxf(m3, s[j + 3]);
  }
  const float mx = fmaxf(fmaxf(m0, m1), fmaxf(m2, m3));

  #pragma unroll
  for (int j = 0; j < 49; ++j) s[j] = __expf(s[j] - mx);

  float t0 = s[48], t1 = 0.f, t2 = 0.f, t3 = 0.f;
  #pragma unroll
  for (int j = 0; j < 48; j += 4) {
    t0 += s[j]; t1 += s[j + 1]; t2 += s[j + 2]; t3 += s[j + 3];
  }
  const float inv = 1.f / ((t0 + t1) + (t2 + t3));
  #pragma unroll
  for (int j = 0; j < 49; ++j) s[j] *= inv;

  f32x2 o2[12];
  #pragma unroll
  for (int dd = 0; dd < 12; ++dd) o2[dd] = (f32x2){0.f, 0.f};
  #pragma unroll
  for (int j = 0; j < 49; ++j) {
    const f32x2 p2 = {s[j], s[j]};
    const float* vr = kv_w + 1176 + j * 24;
    #pragma unroll
    for (int d4 = 0; d4 < 24; d4 += 4) {
      f32x4 vv = *(const f32x4*)(vr + d4);
      o2[(d4 >> 1)]     += p2 * __builtin_shufflevector(vv, vv, 0, 1);
      o2[(d4 >> 1) + 1] += p2 * __builtin_shufflevector(vv, vv, 2, 3);
    }
  }

  if (lane < 49) {
    #pragma unroll
    for (int d4 = 0; d4 < 24; d4 += 4) {
      ushort4 u;
      u.x = f2bfu(o2[(d4 >> 1)][0]);     u.y = f2bfu(o2[(d4 >> 1)][1]);
      u.z = f2bfu(o2[(d4 >> 1) + 1][0]); u.w = f2bfu(o2[(d4 >> 1) + 1][1]);
      *(ushort4*)(qkv_u + myrow * 576 + h * 24 + d4) = u;
    }
  }
}

// -------- depthwise 3x3 conv + bias + tanh-GELU, w-slide x2 -----------------
__global__ __launch_bounds__(192) void dwconv_gelu_kernel(
    const ushort* __restrict__ y1, const float* __restrict__ w,
    const float* __restrict__ bias, ushort* __restrict__ y2)
{
  const int c = threadIdx.x * 4;       // channel group
  const int w0 = blockIdx.y * 2;       // output cols w0, w0+1
  const int b = blockIdx.z;
  const int h0 = blockIdx.x * 28;

  float wt[9][4];
  #pragma unroll
  for (int k = 0; k < 9; ++k)
    #pragma unroll
    for (int j = 0; j < 4; ++j) wt[k][j] = w[(c + j) * 9 + k];
  float bs[4];
  #pragma unroll
  for (int j = 0; j < 4; ++j) bs[j] = bias[c + j];

  const bool okL = (w0 > 0), okR = (w0 + 2 < 112);
  ushort4 rb[6][4];   // rows (ring), cols w0-1..w0+2, packed bf16x4

  auto loadrow = [&](int h, ushort4 dst[4]) {
    const ushort4 z = {0, 0, 0, 0};
    if (h < 0 || h >= 112) {
      dst[0] = z; dst[1] = z; dst[2] = z; dst[3] = z;
      return;
    }
    const ushort* p = y1 + (((size_t)(b * 112 + h)) * 112 + w0) * HID + c;
    dst[0] = okL ? *(const ushort4*)(p - HID) : z;
    dst[1] = *(const ushort4*)(p);
    dst[2] = *(const ushort4*)(p + HID);
    dst[3] = okR ? *(const ushort4*)(p + 2 * HID) : z;
  };

  loadrow(h0 - 1, rb[0]);
  loadrow(h0, rb[1]);

  for (int m = 0; m < 7; ++m) {
    const int hb = h0 + m * 4;
    loadrow(hb + 1, rb[2]);
    loadrow(hb + 2, rb[3]);
    loadrow(hb + 3, rb[4]);
    loadrow(hb + 4, rb[5]);
    #pragma unroll
    for (int o = 0; o < 4; ++o) {
      float acc0[4], acc1[4];
      #pragma unroll
      for (int j = 0; j < 4; ++j) { acc0[j] = bs[j]; acc1[j] = bs[j]; }
      #pragma unroll
      for (int dy = 0; dy < 3; ++dy) {
        float col[4][4];
        #pragma unroll
        for (int x = 0; x < 4; ++x) {
          ushort4 u = rb[o + dy][x];
          col[x][0] = bfu2f(u.x); col[x][1] = bfu2f(u.y);
          col[x][2] = bfu2f(u.z); col[x][3] = bfu2f(u.w);
        }
        #pragma unroll
        for (int dx = 0; dx < 3; ++dx)
          #pragma unroll
          for (int j = 0; j < 4; ++j) {
            acc0[j] += wt[dy * 3 + dx][j] * col[dx][j];
            acc1[j] += wt[dy * 3 + dx][j] * col[dx + 1][j];
          }
      }
      ushort* outp = y2 + (((size_t)(b * 112 + hb + o)) * 112 + w0) * HID + c;
      ushort4 o0, o1;
      o0.x = f2bfu(fgelu(acc0[0])); o0.y = f2bfu(fgelu(acc0[1]));
      o0.z = f2bfu(fgelu(acc0[2])); o0.w = f2bfu(fgelu(acc0[3]));
      o1.x = f2bfu(fgelu(acc1[0])); o1.y = f2bfu(fgelu(acc1[1]));
      o1.z = f2bfu(fgelu(acc1[2])); o1.w = f2bfu(fgelu(acc1[3]));
      *(ushort4*)(outp) = o0;
      *(ushort4*)(outp + HID) = o1;
    }
    #pragma unroll
    for (int x = 0; x < 4; ++x) {
      rb[0][x] = rb[4][x];
      rb[1][x] = rb[5][x];
    }
  }
}

// ---------------------------------------------------------------------------
extern "C" void kernel_launch(void* const* d_in, const int* in_sizes, int n_in,
                              void* d_out, int out_size, void* d_ws, size_t ws_size,
                              hipStream_t stream) {
  const float* x      = (const float*)d_in[0];
  const float* n1g    = (const float*)d_in[1];
  const float* n1b    = (const float*)d_in[2];
  const float* q_w    = (const float*)d_in[3];
  const float* q_b    = (const float*)d_in[4];
  const float* kv_w   = (const float*)d_in[5];
  const float* kv_b   = (const float*)d_in[6];
  const float* rpe    = (const float*)d_in[7];
  const float* proj_w = (const float*)d_in[8];
  const float* proj_b = (const float*)d_in[9];
  const float* n2g    = (const float*)d_in[10];
  const float* n2b    = (const float*)d_in[11];
  const float* fc1_w  = (const float*)d_in[12];
  const float* fc1_b  = (const float*)d_in[13];
  const float* dw_w   = (const float*)d_in[14];
  const float* dw_b   = (const float*)d_in[15];
  const float* fc2_w  = (const float*)d_in[16];
  const float* fc2_b  = (const float*)d_in[17];
  float* out = (float*)d_out;

  // ---- weights at front of ws (~0.9 MB) ----
  char* ws = (char*)d_ws;
  __hip_bfloat16* wcat  = (__hip_bfloat16*)(ws);               // 576*192 bf16
  __hip_bfloat16* projw = (__hip_bfloat16*)(ws + 221184);      // 192*192
  __hip_bfloat16* fc1w  = (__hip_bfloat16*)(ws + 294912);      // 768*192
  __hip_bfloat16* fc2w  = (__hip_bfloat16*)(ws + 589824);      // 192*768
  float* bcat           = (float*)(ws + 884736);               // 576 f32
  const size_t WOFF = 1u << 20;                                // 1 MB

  // ---- pick images-per-chunk CB so the activation buffers fit ws_size ----
  int CB = 8;
  while (CB > 1 && WOFF + (size_t)CB * 12544 * 3456 > ws_size) CB >>= 1;
  const size_t Mc = (size_t)CB * 12544;
  char* Abuf = ws + WOFF;                        // xn / yn   (bf16 Mc x 192)
  char* Bbuf = Abuf + Mc * 384;                  // qkv (Mc x 576) / y2 (Mc x 768)
  char* Cbuf = Bbuf + Mc * 1536;                 // y1 (bf16 Mc x 768)
  __hip_bfloat16* xn  = (__hip_bfloat16*)Abuf;
  __hip_bfloat16* qkv = (__hip_bfloat16*)Bbuf;
  __hip_bfloat16* y2  = (__hip_bfloat16*)Bbuf;
  __hip_bfloat16* y1  = (__hip_bfloat16*)Cbuf;

  prep_kernel<<<576, 256, 0, stream>>>(q_w, q_b, kv_w, kv_b, proj_w, fc1_w,
                                       fc2_w, wcat, bcat, projw, fc1w, fc2w);

  const int nChunks = 8 / CB;
  const int mt = CB * 98;
  for (int cchunk = 0; cchunk < nChunks; ++cchunk) {
    const size_t toff = (size_t)cchunk * Mc;
    const float* xc = x + toff * C_DIM;
    float* oc = out + toff * C_DIM;

    ln_kernel<<<(int)(Mc / 4), 256, 0, stream>>>(xc, n1g, n1b, xn);
    gemmA_kernel<0><<<dim3(1, mt), 512, 0, stream>>>(
        (const ushort*)xn, 192, (const ushort*)wcat, bcat, nullptr, qkv, 576);
    attn_kernel<<<CB * 512, 256, 0, stream>>>(rpe, qkv);
    gemmA_ln_kernel<<<dim3(1, mt), 512, 0, stream>>>(
        (const ushort*)qkv, 576, (const ushort*)projw, proj_b, xc, oc,
        n2g, n2b, xn);
    gemmA_kernel<0><<<dim3(1, mt), 512, 0, stream>>>(
        (const ushort*)xn, 192, (const ushort*)fc1w, fc1_b, nullptr, y1, 768);
    dwconv_gelu_kernel<<<dim3(4, 56, CB), 192, 0, stream>>>(
        (const ushort*)y1, dw_w, dw_b, (ushort*)y2);
    gemmB_kernel<<<dim3(1, mt), 512, 0, stream>>>(
        (const ushort*)y2, (const ushort*)fc2w, fc2_b, oc, oc);
  }
}

// Round 3
// 587.151 us; speedup vs baseline: 1.4009x; 1.0717x over previous
//
#include <hip/hip_runtime.h>
#include <hip/hip_bf16.h>
#include <cmath>

// Problem constants (B=8, H=W=112, C=192, heads=8, hd=24, ps=7, hid=768)
#define C_DIM 192
#define HID 768

typedef __attribute__((ext_vector_type(8))) __bf16 bf16x8;
typedef __attribute__((ext_vector_type(4))) float f32x4;
typedef __attribute__((ext_vector_type(2))) float f32x2;
typedef __attribute__((ext_vector_type(8))) unsigned short u16x8;
typedef __attribute__((ext_vector_type(4))) unsigned int u32x4;

__device__ __forceinline__ void gload_lds16(const void* g, void* l) {
  __builtin_amdgcn_global_load_lds(
      (__attribute__((address_space(1))) void*)(const_cast<void*>(g)),
      (__attribute__((address_space(3))) void*)(l), 16, 0, 0);
}

__device__ __forceinline__ float bfu2f(ushort u) {
  return __uint_as_float((unsigned)u << 16);
}
__device__ __forceinline__ ushort f2bfu(float f) {
  __hip_bfloat16 h = __float2bfloat16(f);
  return *reinterpret_cast<ushort*>(&h);
}
// tanh-form GELU: |err| ~3e-4 << bf16 ulp (validated R5, absmax 0.0156)
__device__ __forceinline__ float fgelu(float x) {
  float z = x * (1.5957691216f + 0.071354816f * x * x);
  return x / (1.f + __expf(-z));
}

// ---------------- prep: weights fp32 -> bf16 (+ fold q scale) ----------------
__global__ __launch_bounds__(256) void prep_kernel(
    const float* __restrict__ q_w, const float* __restrict__ q_b,
    const float* __restrict__ kv_w, const float* __restrict__ kv_b,
    const float* __restrict__ proj_w, const float* __restrict__ fc1_w,
    const float* __restrict__ fc2_w,
    __hip_bfloat16* __restrict__ wcat, float* __restrict__ bcat,
    __hip_bfloat16* __restrict__ projw, __hip_bfloat16* __restrict__ fc1w,
    __hip_bfloat16* __restrict__ fc2w)
{
  int idx = blockIdx.x * 256 + threadIdx.x;
  const float scale = 0.20412414523193154f;  // 24^-0.5
  if (idx < 110592) {
    float v = (idx < 36864) ? q_w[idx] * scale : kv_w[idx - 36864];
    wcat[idx] = __float2bfloat16(v);
  }
  if (idx < 576) bcat[idx] = (idx < 192) ? q_b[idx] * scale : kv_b[idx - 192];
  if (idx < 36864) projw[idx] = __float2bfloat16(proj_w[idx]);
  if (idx < 147456) {
    fc1w[idx] = __float2bfloat16(fc1_w[idx]);
    fc2w[idx] = __float2bfloat16(fc2_w[idx]);
  }
}

// -------- LayerNorm fp32 -> bf16, one wave per token (192 = 64*3) -----------
__global__ __launch_bounds__(256) void ln_kernel(
    const float* __restrict__ x, const float* __restrict__ g,
    const float* __restrict__ b, __hip_bfloat16* __restrict__ out)
{
  int t = blockIdx.x * 4 + (threadIdx.x >> 6);
  int lane = threadIdx.x & 63;
  const float* xr = x + (size_t)t * C_DIM;
  float v0 = xr[lane], v1 = xr[lane + 64], v2 = xr[lane + 128];
  float s = v0 + v1 + v2;
  float sq = v0 * v0 + v1 * v1 + v2 * v2;
  #pragma unroll
  for (int off = 32; off > 0; off >>= 1) {
    s += __shfl_xor(s, off, 64);
    sq += __shfl_xor(sq, off, 64);
  }
  float mean = s * (1.0f / 192.0f);
  float var = sq * (1.0f / 192.0f) - mean * mean;
  float rstd = rsqrtf(var + 1e-5f);
  size_t o = (size_t)t * C_DIM;
  out[o + lane]       = __float2bfloat16((v0 - mean) * rstd * g[lane] + b[lane]);
  out[o + lane + 64]  = __float2bfloat16((v1 - mean) * rstd * g[lane + 64] + b[lane + 64]);
  out[o + lane + 128] = __float2bfloat16((v2 - mean) * rstd * g[lane + 128] + b[lane + 128]);
}

// ===== GEMM variant A: K=192, A-tile LDS-resident, serial n-tiles ===========
template <int EPI>
__global__ __launch_bounds__(512, 4) void gemmA_kernel(
    const ushort* __restrict__ X, int lda, const ushort* __restrict__ W,
    const float* __restrict__ bias, const float* __restrict__ addin,
    void* __restrict__ outp, int N)
{
  __shared__ __align__(16) ushort Al[128 * 192];  // 49152 B
  __shared__ __align__(16) ushort Bl[64 * 192];   // 24576 B
  const int tid = threadIdx.x;
  const int wv = tid >> 6;          // 0..7
  const int lane = tid & 63;
  const int quad = lane >> 4;
  const int m15 = lane & 15;
  const long mBase = (long)blockIdx.y * 128;
  const int NT = N >> 6;

  #pragma unroll
  for (int r = 0; r < 6; ++r) {
    int sI = tid + r * 512;
    int row = sI / 24;
    int cs = sI - row * 24;
    int gc = cs - (row % 24); if (gc < 0) gc += 24;
    gload_lds16(X + (mBase + row) * (long)lda + gc * 8, Al + sI * 8);
  }

  const int rA0 = wv * 16 + m15;
  const int rA0m = rA0 % 24;

  for (int nt = 0; nt < NT; ++nt) {
    __syncthreads();
    #pragma unroll
    for (int r = 0; r < 3; ++r) {
      int sI = tid + r * 512;
      int row = sI / 24;
      int cs = sI - row * 24;
      int gc = cs - (row % 24); if (gc < 0) gc += 24;
      gload_lds16(W + (long)(nt * 64 + row) * 192 + gc * 8, Bl + sI * 8);
    }
    __syncthreads();

    f32x4 acc[4];
    #pragma unroll
    for (int c = 0; c < 4; ++c) acc[c] = (f32x4){0.f, 0.f, 0.f, 0.f};

    #pragma unroll
    for (int ks = 0; ks < 6; ++ks) {
      const int l = ks * 4 + quad;
      int pa0 = l + rA0m; if (pa0 >= 24) pa0 -= 24;
      bf16x8 a0 = *(const bf16x8*)&Al[rA0 * 192 + pa0 * 8];
      #pragma unroll
      for (int ct = 0; ct < 4; ++ct) {
        const int rB = ct * 16 + m15;
        int pb = l + (rB % 24); if (pb >= 24) pb -= 24;
        bf16x8 b = *(const bf16x8*)&Bl[rB * 192 + pb * 8];
        acc[ct] = __builtin_amdgcn_mfma_f32_16x16x32_bf16(a0, b, acc[ct], 0, 0, 0);
      }
    }
    #pragma unroll
    for (int ct = 0; ct < 4; ++ct)
      #pragma unroll
      for (int i = 0; i < 4; ++i) {
        long row = mBase + wv * 16 + quad * 4 + i;
        int col = nt * 64 + ct * 16 + m15;
        float v = acc[ct][i] + bias[col];
        if (EPI == 1) {
          v += addin[row * N + col];
          ((float*)outp)[row * N + col] = v;
        } else {
          ((__hip_bfloat16*)outp)[row * N + col] = __float2bfloat16(v);
        }
      }
  }
}

// ===== GEMM variant A+LN: proj with residual add, f32 out, fused LN ========
__global__ __launch_bounds__(512, 4) void gemmA_ln_kernel(
    const ushort* __restrict__ X, int lda, const ushort* __restrict__ W,
    const float* __restrict__ bias, const float* __restrict__ addin,
    float* __restrict__ outp, const float* __restrict__ lng,
    const float* __restrict__ lnb, __hip_bfloat16* __restrict__ xnout)
{
  __shared__ __align__(16) ushort Al[128 * 192];
  __shared__ __align__(16) ushort Bl[64 * 192];
  const int tid = threadIdx.x;
  const int wv = tid >> 6;
  const int lane = tid & 63;
  const int quad = lane >> 4;
  const int m15 = lane & 15;
  const long mBase = (long)blockIdx.y * 128;

  #pragma unroll
  for (int r = 0; r < 6; ++r) {
    int sI = tid + r * 512;
    int row = sI / 24;
    int cs = sI - row * 24;
    int gc = cs - (row % 24); if (gc < 0) gc += 24;
    gload_lds16(X + (mBase + row) * (long)lda + gc * 8, Al + sI * 8);
  }

  const int rA0 = wv * 16 + m15;
  const int rA0m = rA0 % 24;

  f32x4 acc[3][4];
  #pragma unroll
  for (int n = 0; n < 3; ++n)
    #pragma unroll
    for (int c = 0; c < 4; ++c) acc[n][c] = (f32x4){0.f, 0.f, 0.f, 0.f};

  #pragma unroll
  for (int nt = 0; nt < 3; ++nt) {
    __syncthreads();
    #pragma unroll
    for (int r = 0; r < 3; ++r) {
      int sI = tid + r * 512;
      int row = sI / 24;
      int cs = sI - row * 24;
      int gc = cs - (row % 24); if (gc < 0) gc += 24;
      gload_lds16(W + (long)(nt * 64 + row) * 192 + gc * 8, Bl + sI * 8);
    }
    __syncthreads();
    #pragma unroll
    for (int ks = 0; ks < 6; ++ks) {
      const int l = ks * 4 + quad;
      int pa0 = l + rA0m; if (pa0 >= 24) pa0 -= 24;
      bf16x8 a0 = *(const bf16x8*)&Al[rA0 * 192 + pa0 * 8];
      #pragma unroll
      for (int ct = 0; ct < 4; ++ct) {
        const int rB = ct * 16 + m15;
        int pb = l + (rB % 24); if (pb >= 24) pb -= 24;
        bf16x8 b = *(const bf16x8*)&Bl[rB * 192 + pb * 8];
        acc[nt][ct] = __builtin_amdgcn_mfma_f32_16x16x32_bf16(a0, b, acc[nt][ct], 0, 0, 0);
      }
    }
  }

  float sum_[4], sq_[4];
  #pragma unroll
  for (int i = 0; i < 4; ++i) { sum_[i] = 0.f; sq_[i] = 0.f; }

  #pragma unroll
  for (int nt = 0; nt < 3; ++nt)
    #pragma unroll
    for (int ct = 0; ct < 4; ++ct) {
      int col = nt * 64 + ct * 16 + m15;
      float cb = bias[col];
      #pragma unroll
      for (int i = 0; i < 4; ++i) {
        long row = mBase + wv * 16 + quad * 4 + i;
        float v = acc[nt][ct][i] + cb + addin[row * 192 + col];
        outp[row * 192 + col] = v;
        acc[nt][ct][i] = v;
        sum_[i] += v;
        sq_[i] += v * v;
      }
    }

  float mean_[4], rstd_[4];
  #pragma unroll
  for (int i = 0; i < 4; ++i) {
    float s = sum_[i], q = sq_[i];
    #pragma unroll
    for (int m = 1; m < 16; m <<= 1) {
      s += __shfl_xor(s, m, 64);
      q += __shfl_xor(q, m, 64);
    }
    float mean = s * (1.0f / 192.0f);
    mean_[i] = mean;
    rstd_[i] = rsqrtf(q * (1.0f / 192.0f) - mean * mean + 1e-5f);
  }

  #pragma unroll
  for (int nt = 0; nt < 3; ++nt)
    #pragma unroll
    for (int ct = 0; ct < 4; ++ct) {
      int col = nt * 64 + ct * 16 + m15;
      float cg = lng[col], cbb = lnb[col];
      #pragma unroll
      for (int i = 0; i < 4; ++i) {
        long row = mBase + wv * 16 + quad * 4 + i;
        float v = (acc[nt][ct][i] - mean_[i]) * rstd_[i] * cg + cbb;
        xnout[row * 192 + col] = __float2bfloat16(v);
      }
    }
}

// ===== GEMM variant B: fc2 (K=768, N=192). 4 K-chunks, 3 live n-tile accs ==
__global__ __launch_bounds__(512, 4) void gemmB_kernel(
    const ushort* __restrict__ X, const ushort* __restrict__ W,
    const float* __restrict__ bias, const float* __restrict__ addin,
    float* __restrict__ outp)
{
  __shared__ __align__(16) ushort Al[128 * 192];
  __shared__ __align__(16) ushort Bl[64 * 192];
  const int tid = threadIdx.x;
  const int wv = tid >> 6;
  const int lane = tid & 63;
  const int quad = lane >> 4;
  const int m15 = lane & 15;
  const long mBase = (long)blockIdx.y * 128;

  const int rA0 = wv * 16 + m15;
  const int rA0m = rA0 % 24;

  f32x4 acc[3][4];
  #pragma unroll
  for (int n = 0; n < 3; ++n)
    #pragma unroll
    for (int c = 0; c < 4; ++c) acc[n][c] = (f32x4){0.f, 0.f, 0.f, 0.f};

  for (int kc = 0; kc < 4; ++kc) {
    for (int nt = 0; nt < 3; ++nt) {
      __syncthreads();
      if (nt == 0) {
        #pragma unroll
        for (int r = 0; r < 6; ++r) {
          int sI = tid + r * 512;
          int row = sI / 24;
          int cs = sI - row * 24;
          int gc = cs - (row % 24); if (gc < 0) gc += 24;
          gload_lds16(X + (mBase + row) * 768l + kc * 192 + gc * 8, Al + sI * 8);
        }
      }
      #pragma unroll
      for (int r = 0; r < 3; ++r) {
        int sI = tid + r * 512;
        int row = sI / 24;
        int cs = sI - row * 24;
        int gc = cs - (row % 24); if (gc < 0) gc += 24;
        gload_lds16(W + (long)(nt * 64 + row) * 768 + kc * 192 + gc * 8, Bl + sI * 8);
      }
      __syncthreads();
      #pragma unroll
      for (int ks = 0; ks < 6; ++ks) {
        const int l = ks * 4 + quad;
        int pa0 = l + rA0m; if (pa0 >= 24) pa0 -= 24;
        bf16x8 a0 = *(const bf16x8*)&Al[rA0 * 192 + pa0 * 8];
        #pragma unroll
        for (int ct = 0; ct < 4; ++ct) {
          const int rB = ct * 16 + m15;
          int pb = l + (rB % 24); if (pb >= 24) pb -= 24;
          bf16x8 b = *(const bf16x8*)&Bl[rB * 192 + pb * 8];
          acc[nt][ct] = __builtin_amdgcn_mfma_f32_16x16x32_bf16(a0, b, acc[nt][ct], 0, 0, 0);
        }
      }
    }
  }
  #pragma unroll
  for (int nt = 0; nt < 3; ++nt)
    #pragma unroll
    for (int ct = 0; ct < 4; ++ct)
      #pragma unroll
      for (int i = 0; i < 4; ++i) {
        long row = mBase + wv * 16 + quad * 4 + i;
        int col = nt * 64 + ct * 16 + m15;
        float v = acc[nt][ct][i] + bias[col] + addin[row * 192 + col];
        outp[row * 192 + col] = v;
      }
}

// ============ window attention: MFMA version, one wave per window-head ======
// Prev version was LDS-issue-bound (~600 broadcast ds_read_b128/wave,
// MfmaUtil 0, VALUBusy 46%).  Now:
//  S^T = K.Q^T via mfma_16x16x32_bf16: A=K frags, B=Q^T frags, BOTH loaded
//  straight from global (per-lane 16B rows: row=lane&15, k=quad*8+e).
//  K quad3 (d=24..31 pad) zeroed in-register (one zero operand suffices).
//  Bias pre-loads the accumulator (C-in).  S^T layout: col r=m15,
//  row j=quad*4+i  ->  softmax over j = 16 in-lane + shfl_xor(16,32).
//  P -> bf16 (v_cvt_pk_bf16_f32) -> XOR-swizzled per-wave LDS tile ->
//  re-read as A-frags (b128) for O = P.V.  V staged bf16 row-major with
//  quad-spreading XOR (((j>>3)&3)<<5); B-frags via 16 u16 gathers/frag.
//  j>=49 masked to -1e30 pre-exp (exp->0); V pad rows zeroed (no 0*NaN);
//  r>=49 / d>=24 only ever reach discarded outputs.  No __syncthreads
//  (all LDS strictly per-wave).
__global__ __launch_bounds__(256, 3) void attn_kernel(
    const float* __restrict__ rpe, __hip_bfloat16* __restrict__ qkv)
{
  __shared__ __align__(16) char smem[51968];
  const int tid = threadIdx.x;
  const int lane = tid & 63;
  const int wv = tid >> 6;
  const int quad = lane >> 4;
  const int m15 = lane & 15;
  const int wh = blockIdx.x * 4 + wv;
  const int h = wh & 7;
  const int win = wh >> 3;
  const int b = win >> 8;
  const int wl = win & 255;
  const int whi = wl >> 4;
  const int wwi = wl & 15;
  ushort* qkv_u = (ushort*)qkv;
  char* Vb = smem + wv * 4096;                       // V: [64 j][32 d] bf16
  char* Pb = smem + 16384 + wv * 8192;               // P: [64 r][64 j] bf16
  float* biasW = (float*)(smem + 49152 + wv * 704);  // 169 f32

  const long rowbase = (long)b * 12544 + (long)(whi * 7) * 112 + wwi * 7;

  // ---- stage V rows (swizzled) ; zero pad rows 49..63 (K-dim safety) ----
  {
    int j = lane;
    int f = ((j >> 3) & 3) << 5;
    if (j < 49) {
      int py = j / 7, px = j - py * 7;
      long row = rowbase + py * 112 + px;
      const ushort* src = qkv_u + row * 576 + 384 + h * 24;
      #pragma unroll
      for (int c = 0; c < 3; ++c) {
        u16x8 val = *(const u16x8*)(src + c * 8);
        *(u16x8*)(Vb + ((j * 64 + c * 16) ^ f)) = val;
      }
    } else {
      u16x8 z = {};
      #pragma unroll
      for (int c = 0; c < 4; ++c)
        *(u16x8*)(Vb + ((j * 64 + c * 16) ^ f)) = z;
    }
  }
  for (int r = lane; r < 169; r += 64) biasW[r] = rpe[r * 8 + h];

  // ---- relative-position index components ----
  int bi[4];
  #pragma unroll
  for (int rt = 0; rt < 4; ++rt) {
    int r = rt * 16 + m15; if (r > 48) r = 48;
    bi[rt] = (r / 7) * 13 + (r % 7) + 84;
  }
  int bj4[4][4];
  #pragma unroll
  for (int jt = 0; jt < 4; ++jt)
    #pragma unroll
    for (int i = 0; i < 4; ++i) {
      int j = jt * 16 + quad * 4 + i; if (j > 48) j = 48;
      bj4[jt][i] = (j / 7) * 13 + (j % 7);
    }

  // ---- S^T accumulators, bias as C-in ----
  f32x4 sacc[4][4];  // [jt][rt]
  #pragma unroll
  for (int jt = 0; jt < 4; ++jt)
    #pragma unroll
    for (int rt = 0; rt < 4; ++rt)
      #pragma unroll
      for (int i = 0; i < 4; ++i)
        sacc[jt][rt][i] = biasW[bi[rt] - bj4[jt][i]];

  // ---- K / Q fragments straight from global ----
  bf16x8 kf[4], qf[4];
  const bf16x8 zf = {};
  #pragma unroll
  for (int jt = 0; jt < 4; ++jt) {
    int t = jt * 16 + m15; if (t > 48) t = 48;
    long row = rowbase + (t / 7) * 112 + (t % 7);
    kf[jt] = *(const bf16x8*)(qkv_u + row * 576 + 192 + h * 24 + quad * 8);
    if (quad == 3) kf[jt] = zf;   // zero d=24..31 pad (one side zero -> ok)
  }
  #pragma unroll
  for (int rt = 0; rt < 4; ++rt) {
    int t = rt * 16 + m15; if (t > 48) t = 48;
    long row = rowbase + (t / 7) * 112 + (t % 7);
    qf[rt] = *(const bf16x8*)(qkv_u + row * 576 + h * 24 + quad * 8);
  }
  #pragma unroll
  for (int jt = 0; jt < 4; ++jt)
    #pragma unroll
    for (int rt = 0; rt < 4; ++rt)
      sacc[jt][rt] = __builtin_amdgcn_mfma_f32_16x16x32_bf16(
          kf[jt], qf[rt], sacc[jt][rt], 0, 0, 0);

  // ---- mask j >= 49 (jt=3: j = 48 + quad*4 + i) ----
  #pragma unroll
  for (int rt = 0; rt < 4; ++rt) {
    if (quad != 0) sacc[3][rt][0] = -1e30f;
    sacc[3][rt][1] = -1e30f;
    sacc[3][rt][2] = -1e30f;
    sacc[3][rt][3] = -1e30f;
  }

  // ---- softmax over j per r-column (unnormalized; inv kept per rt) ----
  float inv[4];
  #pragma unroll
  for (int rt = 0; rt < 4; ++rt) {
    float mx = sacc[0][rt][0];
    #pragma unroll
    for (int jt = 0; jt < 4; ++jt)
      #pragma unroll
      for (int i = 0; i < 4; ++i)
        mx = fmaxf(mx, sacc[jt][rt][i]);
    mx = fmaxf(mx, __shfl_xor(mx, 16, 64));
    mx = fmaxf(mx, __shfl_xor(mx, 32, 64));
    float sum = 0.f;
    #pragma unroll
    for (int jt = 0; jt < 4; ++jt)
      #pragma unroll
      for (int i = 0; i < 4; ++i) {
        float p = __expf(sacc[jt][rt][i] - mx);
        sacc[jt][rt][i] = p;
        sum += p;
      }
    sum += __shfl_xor(sum, 16, 64);
    sum += __shfl_xor(sum, 32, 64);
    inv[rt] = 1.f / sum;
  }

  // ---- P -> bf16 -> swizzled LDS ([64 r][64 j], byte ^= (m15&7)<<4) ----
  const int swzP = (m15 & 7) << 4;
  #pragma unroll
  for (int rt = 0; rt < 4; ++rt)
    #pragma unroll
    for (int jt = 0; jt < 4; ++jt)
      #pragma unroll
      for (int u = 0; u < 2; ++u) {
        unsigned pk;
        asm("v_cvt_pk_bf16_f32 %0, %1, %2"
            : "=v"(pk)
            : "v"(sacc[jt][rt][2 * u]), "v"(sacc[jt][rt][2 * u + 1]));
        int j0 = jt * 16 + quad * 4 + 2 * u;
        int lin = (rt * 16 + m15) * 128 + j0 * 2;
        *(unsigned*)(Pb + (lin ^ swzP)) = pk;
      }

  // ---- O = P.V ----
  f32x4 oacc[4][2];
  #pragma unroll
  for (int mt = 0; mt < 4; ++mt)
    #pragma unroll
    for (int nt = 0; nt < 2; ++nt) oacc[mt][nt] = (f32x4){0.f, 0.f, 0.f, 0.f};

  #pragma unroll
  for (int kt = 0; kt < 2; ++kt) {
    bf16x8 pf[4];
    #pragma unroll
    for (int mt = 0; mt < 4; ++mt) {
      int lin = (mt * 16 + m15) * 128 + kt * 64 + quad * 16;
      pf[mt] = *(const bf16x8*)(Pb + (lin ^ swzP));
    }
    bf16x8 vf[2];
    #pragma unroll
    for (int nt = 0; nt < 2; ++nt) {
      u32x4 w;
      #pragma unroll
      for (int e2 = 0; e2 < 4; ++e2) {
        int j_lo = kt * 32 + quad * 8 + 2 * e2;
        int lin_lo = j_lo * 64 + (nt * 16 + m15) * 2;
        int lin_hi = lin_lo + 64;
        unsigned lo = *(const ushort*)(Vb + (lin_lo ^ (quad << 5)));
        unsigned hi = *(const ushort*)(Vb + (lin_hi ^ (quad << 5)));
        w[e2] = lo | (hi << 16);
      }
      vf[nt] = __builtin_bit_cast(bf16x8, w);
    }
    #pragma unroll
    for (int mt = 0; mt < 4; ++mt)
      #pragma unroll
      for (int nt = 0; nt < 2; ++nt)
        oacc[mt][nt] = __builtin_amdgcn_mfma_f32_16x16x32_bf16(
            pf[mt], vf[nt], oacc[mt][nt], 0, 0, 0);
  }

  // ---- normalize (redistribute inv via bpermute) + store ----
  #pragma unroll
  for (int mt = 0; mt < 4; ++mt)
    #pragma unroll
    for (int i = 0; i < 4; ++i) {
      float iv = __shfl(inv[mt], quad * 4 + i, 64);
      int r = mt * 16 + quad * 4 + i;
      if (r < 49) {
        long row = rowbase + (r / 7) * 112 + (r % 7);
        ushort* dst = qkv_u + row * 576 + h * 24;
        dst[m15] = f2bfu(oacc[mt][0][i] * iv);
        if (m15 < 8) dst[16 + m15] = f2bfu(oacc[mt][1][i] * iv);
      }
    }
}

// -------- depthwise 3x3 conv + bias + tanh-GELU, w-slide x2 -----------------
__global__ __launch_bounds__(192) void dwconv_gelu_kernel(
    const ushort* __restrict__ y1, const float* __restrict__ w,
    const float* __restrict__ bias, ushort* __restrict__ y2)
{
  const int c = threadIdx.x * 4;       // channel group
  const int w0 = blockIdx.y * 2;       // output cols w0, w0+1
  const int b = blockIdx.z;
  const int h0 = blockIdx.x * 28;

  float wt[9][4];
  #pragma unroll
  for (int k = 0; k < 9; ++k)
    #pragma unroll
    for (int j = 0; j < 4; ++j) wt[k][j] = w[(c + j) * 9 + k];
  float bs[4];
  #pragma unroll
  for (int j = 0; j < 4; ++j) bs[j] = bias[c + j];

  const bool okL = (w0 > 0), okR = (w0 + 2 < 112);
  ushort4 rb[6][4];   // rows (ring), cols w0-1..w0+2, packed bf16x4

  auto loadrow = [&](int h, ushort4 dst[4]) {
    const ushort4 z = {0, 0, 0, 0};
    if (h < 0 || h >= 112) {
      dst[0] = z; dst[1] = z; dst[2] = z; dst[3] = z;
      return;
    }
    const ushort* p = y1 + (((size_t)(b * 112 + h)) * 112 + w0) * HID + c;
    dst[0] = okL ? *(const ushort4*)(p - HID) : z;
    dst[1] = *(const ushort4*)(p);
    dst[2] = *(const ushort4*)(p + HID);
    dst[3] = okR ? *(const ushort4*)(p + 2 * HID) : z;
  };

  loadrow(h0 - 1, rb[0]);
  loadrow(h0, rb[1]);

  for (int m = 0; m < 7; ++m) {
    const int hb = h0 + m * 4;
    loadrow(hb + 1, rb[2]);
    loadrow(hb + 2, rb[3]);
    loadrow(hb + 3, rb[4]);
    loadrow(hb + 4, rb[5]);
    #pragma unroll
    for (int o = 0; o < 4; ++o) {
      float acc0[4], acc1[4];
      #pragma unroll
      for (int j = 0; j < 4; ++j) { acc0[j] = bs[j]; acc1[j] = bs[j]; }
      #pragma unroll
      for (int dy = 0; dy < 3; ++dy) {
        float col[4][4];
        #pragma unroll
        for (int x = 0; x < 4; ++x) {
          ushort4 u = rb[o + dy][x];
          col[x][0] = bfu2f(u.x); col[x][1] = bfu2f(u.y);
          col[x][2] = bfu2f(u.z); col[x][3] = bfu2f(u.w);
        }
        #pragma unroll
        for (int dx = 0; dx < 3; ++dx)
          #pragma unroll
          for (int j = 0; j < 4; ++j) {
            acc0[j] += wt[dy * 3 + dx][j] * col[dx][j];
            acc1[j] += wt[dy * 3 + dx][j] * col[dx + 1][j];
          }
      }
      ushort* outp = y2 + (((size_t)(b * 112 + hb + o)) * 112 + w0) * HID + c;
      ushort4 o0, o1;
      o0.x = f2bfu(fgelu(acc0[0])); o0.y = f2bfu(fgelu(acc0[1]));
      o0.z = f2bfu(fgelu(acc0[2])); o0.w = f2bfu(fgelu(acc0[3]));
      o1.x = f2bfu(fgelu(acc1[0])); o1.y = f2bfu(fgelu(acc1[1]));
      o1.z = f2bfu(fgelu(acc1[2])); o1.w = f2bfu(fgelu(acc1[3]));
      *(ushort4*)(outp) = o0;
      *(ushort4*)(outp + HID) = o1;
    }
    #pragma unroll
    for (int x = 0; x < 4; ++x) {
      rb[0][x] = rb[4][x];
      rb[1][x] = rb[5][x];
    }
  }
}

// ---------------------------------------------------------------------------
extern "C" void kernel_launch(void* const* d_in, const int* in_sizes, int n_in,
                              void* d_out, int out_size, void* d_ws, size_t ws_size,
                              hipStream_t stream) {
  const float* x      = (const float*)d_in[0];
  const float* n1g    = (const float*)d_in[1];
  const float* n1b    = (const float*)d_in[2];
  const float* q_w    = (const float*)d_in[3];
  const float* q_b    = (const float*)d_in[4];
  const float* kv_w   = (const float*)d_in[5];
  const float* kv_b   = (const float*)d_in[6];
  const float* rpe    = (const float*)d_in[7];
  const float* proj_w = (const float*)d_in[8];
  const float* proj_b = (const float*)d_in[9];
  const float* n2g    = (const float*)d_in[10];
  const float* n2b    = (const float*)d_in[11];
  const float* fc1_w  = (const float*)d_in[12];
  const float* fc1_b  = (const float*)d_in[13];
  const float* dw_w   = (const float*)d_in[14];
  const float* dw_b   = (const float*)d_in[15];
  const float* fc2_w  = (const float*)d_in[16];
  const float* fc2_b  = (const float*)d_in[17];
  float* out = (float*)d_out;

  // ---- weights at front of ws (~0.9 MB) ----
  char* ws = (char*)d_ws;
  __hip_bfloat16* wcat  = (__hip_bfloat16*)(ws);               // 576*192 bf16
  __hip_bfloat16* projw = (__hip_bfloat16*)(ws + 221184);      // 192*192
  __hip_bfloat16* fc1w  = (__hip_bfloat16*)(ws + 294912);      // 768*192
  __hip_bfloat16* fc2w  = (__hip_bfloat16*)(ws + 589824);      // 192*768
  float* bcat           = (float*)(ws + 884736);               // 576 f32
  const size_t WOFF = 1u << 20;                                // 1 MB

  // ---- pick images-per-chunk CB so the activation buffers fit ws_size ----
  int CB = 8;
  while (CB > 1 && WOFF + (size_t)CB * 12544 * 3456 > ws_size) CB >>= 1;
  const size_t Mc = (size_t)CB * 12544;
  char* Abuf = ws + WOFF;                        // xn / yn   (bf16 Mc x 192)
  char* Bbuf = Abuf + Mc * 384;                  // qkv (Mc x 576) / y2 (Mc x 768)
  char* Cbuf = Bbuf + Mc * 1536;                 // y1 (bf16 Mc x 768)
  __hip_bfloat16* xn  = (__hip_bfloat16*)Abuf;
  __hip_bfloat16* qkv = (__hip_bfloat16*)Bbuf;
  __hip_bfloat16* y2  = (__hip_bfloat16*)Bbuf;
  __hip_bfloat16* y1  = (__hip_bfloat16*)Cbuf;

  prep_kernel<<<576, 256, 0, stream>>>(q_w, q_b, kv_w, kv_b, proj_w, fc1_w,
                                       fc2_w, wcat, bcat, projw, fc1w, fc2w);

  const int nChunks = 8 / CB;
  const int mt = CB * 98;
  for (int cchunk = 0; cchunk < nChunks; ++cchunk) {
    const size_t toff = (size_t)cchunk * Mc;
    const float* xc = x + toff * C_DIM;
    float* oc = out + toff * C_DIM;

    ln_kernel<<<(int)(Mc / 4), 256, 0, stream>>>(xc, n1g, n1b, xn);
    gemmA_kernel<0><<<dim3(1, mt), 512, 0, stream>>>(
        (const ushort*)xn, 192, (const ushort*)wcat, bcat, nullptr, qkv, 576);
    attn_kernel<<<CB * 512, 256, 0, stream>>>(rpe, qkv);
    gemmA_ln_kernel<<<dim3(1, mt), 512, 0, stream>>>(
        (const ushort*)qkv, 576, (const ushort*)projw, proj_b, xc, oc,
        n2g, n2b, xn);
    gemmA_kernel<0><<<dim3(1, mt), 512, 0, stream>>>(
        (const ushort*)xn, 192, (const ushort*)fc1w, fc1_b, nullptr, y1, 768);
    dwconv_gelu_kernel<<<dim3(4, 56, CB), 192, 0, stream>>>(
        (const ushort*)y1, dw_w, dw_b, (ushort*)y2);
    gemmB_kernel<<<dim3(1, mt), 512, 0, stream>>>(
        (const ushort*)y2, (const ushort*)fc2w, fc2_b, oc, oc);
  }
}

// Round 4
// 586.944 us; speedup vs baseline: 1.4014x; 1.0004x over previous
//
#include <hip/hip_runtime.h>
#include <hip/hip_bf16.h>
#include <cmath>

// Problem constants (B=8, H=W=112, C=192, heads=8, hd=24, ps=7, hid=768)
#define C_DIM 192
#define HID 768

typedef __attribute__((ext_vector_type(8))) __bf16 bf16x8;
typedef __attribute__((ext_vector_type(4))) float f32x4;
typedef __attribute__((ext_vector_type(2))) float f32x2;
typedef __attribute__((ext_vector_type(8))) unsigned short u16x8;
typedef __attribute__((ext_vector_type(4))) unsigned int u32x4;

__device__ __forceinline__ void gload_lds16(const void* g, void* l) {
  __builtin_amdgcn_global_load_lds(
      (__attribute__((address_space(1))) void*)(const_cast<void*>(g)),
      (__attribute__((address_space(3))) void*)(l), 16, 0, 0);
}

__device__ __forceinline__ float bfu2f(ushort u) {
  return __uint_as_float((unsigned)u << 16);
}
__device__ __forceinline__ ushort f2bfu(float f) {
  __hip_bfloat16 h = __float2bfloat16(f);
  return *reinterpret_cast<ushort*>(&h);
}
// tanh-form GELU: |err| ~3e-4 << bf16 ulp (validated R5, absmax 0.0156)
__device__ __forceinline__ float fgelu(float x) {
  float z = x * (1.5957691216f + 0.071354816f * x * x);
  return x / (1.f + __expf(-z));
}

// ---------------- prep: weights fp32 -> bf16 (+ fold q scale) ----------------
__global__ __launch_bounds__(256) void prep_kernel(
    const float* __restrict__ q_w, const float* __restrict__ q_b,
    const float* __restrict__ kv_w, const float* __restrict__ kv_b,
    const float* __restrict__ proj_w, const float* __restrict__ fc1_w,
    const float* __restrict__ fc2_w,
    __hip_bfloat16* __restrict__ wcat, float* __restrict__ bcat,
    __hip_bfloat16* __restrict__ projw, __hip_bfloat16* __restrict__ fc1w,
    __hip_bfloat16* __restrict__ fc2w)
{
  int idx = blockIdx.x * 256 + threadIdx.x;
  const float scale = 0.20412414523193154f;  // 24^-0.5
  if (idx < 110592) {
    float v = (idx < 36864) ? q_w[idx] * scale : kv_w[idx - 36864];
    wcat[idx] = __float2bfloat16(v);
  }
  if (idx < 576) bcat[idx] = (idx < 192) ? q_b[idx] * scale : kv_b[idx - 192];
  if (idx < 36864) projw[idx] = __float2bfloat16(proj_w[idx]);
  if (idx < 147456) {
    fc1w[idx] = __float2bfloat16(fc1_w[idx]);
    fc2w[idx] = __float2bfloat16(fc2_w[idx]);
  }
}

// -------- LayerNorm fp32 -> bf16, one wave per token (192 = 64*3) -----------
__global__ __launch_bounds__(256) void ln_kernel(
    const float* __restrict__ x, const float* __restrict__ g,
    const float* __restrict__ b, __hip_bfloat16* __restrict__ out)
{
  int t = blockIdx.x * 4 + (threadIdx.x >> 6);
  int lane = threadIdx.x & 63;
  const float* xr = x + (size_t)t * C_DIM;
  float v0 = xr[lane], v1 = xr[lane + 64], v2 = xr[lane + 128];
  float s = v0 + v1 + v2;
  float sq = v0 * v0 + v1 * v1 + v2 * v2;
  #pragma unroll
  for (int off = 32; off > 0; off >>= 1) {
    s += __shfl_xor(s, off, 64);
    sq += __shfl_xor(sq, off, 64);
  }
  float mean = s * (1.0f / 192.0f);
  float var = sq * (1.0f / 192.0f) - mean * mean;
  float rstd = rsqrtf(var + 1e-5f);
  size_t o = (size_t)t * C_DIM;
  out[o + lane]       = __float2bfloat16((v0 - mean) * rstd * g[lane] + b[lane]);
  out[o + lane + 64]  = __float2bfloat16((v1 - mean) * rstd * g[lane + 64] + b[lane + 64]);
  out[o + lane + 128] = __float2bfloat16((v2 - mean) * rstd * g[lane + 128] + b[lane + 128]);
}

// ===== GEMM variant A: K=192, A-tile LDS-resident, serial n-tiles ===========
template <int EPI>
__global__ __launch_bounds__(512, 4) void gemmA_kernel(
    const ushort* __restrict__ X, int lda, const ushort* __restrict__ W,
    const float* __restrict__ bias, const float* __restrict__ addin,
    void* __restrict__ outp, int N)
{
  __shared__ __align__(16) ushort Al[128 * 192];  // 49152 B
  __shared__ __align__(16) ushort Bl[64 * 192];   // 24576 B
  const int tid = threadIdx.x;
  const int wv = tid >> 6;          // 0..7
  const int lane = tid & 63;
  const int quad = lane >> 4;
  const int m15 = lane & 15;
  const long mBase = (long)blockIdx.y * 128;
  const int NT = N >> 6;

  #pragma unroll
  for (int r = 0; r < 6; ++r) {
    int sI = tid + r * 512;
    int row = sI / 24;
    int cs = sI - row * 24;
    int gc = cs - (row % 24); if (gc < 0) gc += 24;
    gload_lds16(X + (mBase + row) * (long)lda + gc * 8, Al + sI * 8);
  }

  const int rA0 = wv * 16 + m15;
  const int rA0m = rA0 % 24;

  for (int nt = 0; nt < NT; ++nt) {
    __syncthreads();
    #pragma unroll
    for (int r = 0; r < 3; ++r) {
      int sI = tid + r * 512;
      int row = sI / 24;
      int cs = sI - row * 24;
      int gc = cs - (row % 24); if (gc < 0) gc += 24;
      gload_lds16(W + (long)(nt * 64 + row) * 192 + gc * 8, Bl + sI * 8);
    }
    __syncthreads();

    f32x4 acc[4];
    #pragma unroll
    for (int c = 0; c < 4; ++c) acc[c] = (f32x4){0.f, 0.f, 0.f, 0.f};

    #pragma unroll
    for (int ks = 0; ks < 6; ++ks) {
      const int l = ks * 4 + quad;
      int pa0 = l + rA0m; if (pa0 >= 24) pa0 -= 24;
      bf16x8 a0 = *(const bf16x8*)&Al[rA0 * 192 + pa0 * 8];
      #pragma unroll
      for (int ct = 0; ct < 4; ++ct) {
        const int rB = ct * 16 + m15;
        int pb = l + (rB % 24); if (pb >= 24) pb -= 24;
        bf16x8 b = *(const bf16x8*)&Bl[rB * 192 + pb * 8];
        acc[ct] = __builtin_amdgcn_mfma_f32_16x16x32_bf16(a0, b, acc[ct], 0, 0, 0);
      }
    }
    #pragma unroll
    for (int ct = 0; ct < 4; ++ct)
      #pragma unroll
      for (int i = 0; i < 4; ++i) {
        long row = mBase + wv * 16 + quad * 4 + i;
        int col = nt * 64 + ct * 16 + m15;
        float v = acc[ct][i] + bias[col];
        if (EPI == 1) {
          v += addin[row * N + col];
          ((float*)outp)[row * N + col] = v;
        } else {
          ((__hip_bfloat16*)outp)[row * N + col] = __float2bfloat16(v);
        }
      }
  }
}

// ===== GEMM variant A+LN: proj with residual add, f32 out, fused LN ========
__global__ __launch_bounds__(512, 4) void gemmA_ln_kernel(
    const ushort* __restrict__ X, int lda, const ushort* __restrict__ W,
    const float* __restrict__ bias, const float* __restrict__ addin,
    float* __restrict__ outp, const float* __restrict__ lng,
    const float* __restrict__ lnb, __hip_bfloat16* __restrict__ xnout)
{
  __shared__ __align__(16) ushort Al[128 * 192];
  __shared__ __align__(16) ushort Bl[64 * 192];
  const int tid = threadIdx.x;
  const int wv = tid >> 6;
  const int lane = tid & 63;
  const int quad = lane >> 4;
  const int m15 = lane & 15;
  const long mBase = (long)blockIdx.y * 128;

  #pragma unroll
  for (int r = 0; r < 6; ++r) {
    int sI = tid + r * 512;
    int row = sI / 24;
    int cs = sI - row * 24;
    int gc = cs - (row % 24); if (gc < 0) gc += 24;
    gload_lds16(X + (mBase + row) * (long)lda + gc * 8, Al + sI * 8);
  }

  const int rA0 = wv * 16 + m15;
  const int rA0m = rA0 % 24;

  f32x4 acc[3][4];
  #pragma unroll
  for (int n = 0; n < 3; ++n)
    #pragma unroll
    for (int c = 0; c < 4; ++c) acc[n][c] = (f32x4){0.f, 0.f, 0.f, 0.f};

  #pragma unroll
  for (int nt = 0; nt < 3; ++nt) {
    __syncthreads();
    #pragma unroll
    for (int r = 0; r < 3; ++r) {
      int sI = tid + r * 512;
      int row = sI / 24;
      int cs = sI - row * 24;
      int gc = cs - (row % 24); if (gc < 0) gc += 24;
      gload_lds16(W + (long)(nt * 64 + row) * 192 + gc * 8, Bl + sI * 8);
    }
    __syncthreads();
    #pragma unroll
    for (int ks = 0; ks < 6; ++ks) {
      const int l = ks * 4 + quad;
      int pa0 = l + rA0m; if (pa0 >= 24) pa0 -= 24;
      bf16x8 a0 = *(const bf16x8*)&Al[rA0 * 192 + pa0 * 8];
      #pragma unroll
      for (int ct = 0; ct < 4; ++ct) {
        const int rB = ct * 16 + m15;
        int pb = l + (rB % 24); if (pb >= 24) pb -= 24;
        bf16x8 b = *(const bf16x8*)&Bl[rB * 192 + pb * 8];
        acc[nt][ct] = __builtin_amdgcn_mfma_f32_16x16x32_bf16(a0, b, acc[nt][ct], 0, 0, 0);
      }
    }
  }

  float sum_[4], sq_[4];
  #pragma unroll
  for (int i = 0; i < 4; ++i) { sum_[i] = 0.f; sq_[i] = 0.f; }

  #pragma unroll
  for (int nt = 0; nt < 3; ++nt)
    #pragma unroll
    for (int ct = 0; ct < 4; ++ct) {
      int col = nt * 64 + ct * 16 + m15;
      float cb = bias[col];
      #pragma unroll
      for (int i = 0; i < 4; ++i) {
        long row = mBase + wv * 16 + quad * 4 + i;
        float v = acc[nt][ct][i] + cb + addin[row * 192 + col];
        outp[row * 192 + col] = v;
        acc[nt][ct][i] = v;
        sum_[i] += v;
        sq_[i] += v * v;
      }
    }

  float mean_[4], rstd_[4];
  #pragma unroll
  for (int i = 0; i < 4; ++i) {
    float s = sum_[i], q = sq_[i];
    #pragma unroll
    for (int m = 1; m < 16; m <<= 1) {
      s += __shfl_xor(s, m, 64);
      q += __shfl_xor(q, m, 64);
    }
    float mean = s * (1.0f / 192.0f);
    mean_[i] = mean;
    rstd_[i] = rsqrtf(q * (1.0f / 192.0f) - mean * mean + 1e-5f);
  }

  #pragma unroll
  for (int nt = 0; nt < 3; ++nt)
    #pragma unroll
    for (int ct = 0; ct < 4; ++ct) {
      int col = nt * 64 + ct * 16 + m15;
      float cg = lng[col], cbb = lnb[col];
      #pragma unroll
      for (int i = 0; i < 4; ++i) {
        long row = mBase + wv * 16 + quad * 4 + i;
        float v = (acc[nt][ct][i] - mean_[i]) * rstd_[i] * cg + cbb;
        xnout[row * 192 + col] = __float2bfloat16(v);
      }
    }
}

// ===== GEMM variant B: fc2 (K=768, N=192). 4 K-chunks, 3 live n-tile accs ==
__global__ __launch_bounds__(512, 4) void gemmB_kernel(
    const ushort* __restrict__ X, const ushort* __restrict__ W,
    const float* __restrict__ bias, const float* __restrict__ addin,
    float* __restrict__ outp)
{
  __shared__ __align__(16) ushort Al[128 * 192];
  __shared__ __align__(16) ushort Bl[64 * 192];
  const int tid = threadIdx.x;
  const int wv = tid >> 6;
  const int lane = tid & 63;
  const int quad = lane >> 4;
  const int m15 = lane & 15;
  const long mBase = (long)blockIdx.y * 128;

  const int rA0 = wv * 16 + m15;
  const int rA0m = rA0 % 24;

  f32x4 acc[3][4];
  #pragma unroll
  for (int n = 0; n < 3; ++n)
    #pragma unroll
    for (int c = 0; c < 4; ++c) acc[n][c] = (f32x4){0.f, 0.f, 0.f, 0.f};

  for (int kc = 0; kc < 4; ++kc) {
    for (int nt = 0; nt < 3; ++nt) {
      __syncthreads();
      if (nt == 0) {
        #pragma unroll
        for (int r = 0; r < 6; ++r) {
          int sI = tid + r * 512;
          int row = sI / 24;
          int cs = sI - row * 24;
          int gc = cs - (row % 24); if (gc < 0) gc += 24;
          gload_lds16(X + (mBase + row) * 768l + kc * 192 + gc * 8, Al + sI * 8);
        }
      }
      #pragma unroll
      for (int r = 0; r < 3; ++r) {
        int sI = tid + r * 512;
        int row = sI / 24;
        int cs = sI - row * 24;
        int gc = cs - (row % 24); if (gc < 0) gc += 24;
        gload_lds16(W + (long)(nt * 64 + row) * 768 + kc * 192 + gc * 8, Bl + sI * 8);
      }
      __syncthreads();
      #pragma unroll
      for (int ks = 0; ks < 6; ++ks) {
        const int l = ks * 4 + quad;
        int pa0 = l + rA0m; if (pa0 >= 24) pa0 -= 24;
        bf16x8 a0 = *(const bf16x8*)&Al[rA0 * 192 + pa0 * 8];
        #pragma unroll
        for (int ct = 0; ct < 4; ++ct) {
          const int rB = ct * 16 + m15;
          int pb = l + (rB % 24); if (pb >= 24) pb -= 24;
          bf16x8 b = *(const bf16x8*)&Bl[rB * 192 + pb * 8];
          acc[nt][ct] = __builtin_amdgcn_mfma_f32_16x16x32_bf16(a0, b, acc[nt][ct], 0, 0, 0);
        }
      }
    }
  }
  #pragma unroll
  for (int nt = 0; nt < 3; ++nt)
    #pragma unroll
    for (int ct = 0; ct < 4; ++ct)
      #pragma unroll
      for (int i = 0; i < 4; ++i) {
        long row = mBase + wv * 16 + quad * 4 + i;
        int col = nt * 64 + ct * 16 + m15;
        float v = acc[nt][ct][i] + bias[col] + addin[row * 192 + col];
        outp[row * 192 + col] = v;
      }
}

// ============ window attention: MFMA version, one wave per window-head ======
__global__ __launch_bounds__(256, 3) void attn_kernel(
    const float* __restrict__ rpe, __hip_bfloat16* __restrict__ qkv)
{
  __shared__ __align__(16) char smem[51968];
  const int tid = threadIdx.x;
  const int lane = tid & 63;
  const int wv = tid >> 6;
  const int quad = lane >> 4;
  const int m15 = lane & 15;
  const int wh = blockIdx.x * 4 + wv;
  const int h = wh & 7;
  const int win = wh >> 3;
  const int b = win >> 8;
  const int wl = win & 255;
  const int whi = wl >> 4;
  const int wwi = wl & 15;
  ushort* qkv_u = (ushort*)qkv;
  char* Vb = smem + wv * 4096;                       // V: [64 j][32 d] bf16
  char* Pb = smem + 16384 + wv * 8192;               // P: [64 r][64 j] bf16
  float* biasW = (float*)(smem + 49152 + wv * 704);  // 169 f32

  const long rowbase = (long)b * 12544 + (long)(whi * 7) * 112 + wwi * 7;

  // ---- stage V rows (swizzled) ; zero pad rows 49..63 (K-dim safety) ----
  {
    int j = lane;
    int f = ((j >> 3) & 3) << 5;
    if (j < 49) {
      int py = j / 7, px = j - py * 7;
      long row = rowbase + py * 112 + px;
      const ushort* src = qkv_u + row * 576 + 384 + h * 24;
      #pragma unroll
      for (int c = 0; c < 3; ++c) {
        u16x8 val = *(const u16x8*)(src + c * 8);
        *(u16x8*)(Vb + ((j * 64 + c * 16) ^ f)) = val;
      }
    } else {
      u16x8 z = {};
      #pragma unroll
      for (int c = 0; c < 4; ++c)
        *(u16x8*)(Vb + ((j * 64 + c * 16) ^ f)) = z;
    }
  }
  for (int r = lane; r < 169; r += 64) biasW[r] = rpe[r * 8 + h];

  // ---- relative-position index components ----
  int bi[4];
  #pragma unroll
  for (int rt = 0; rt < 4; ++rt) {
    int r = rt * 16 + m15; if (r > 48) r = 48;
    bi[rt] = (r / 7) * 13 + (r % 7) + 84;
  }
  int bj4[4][4];
  #pragma unroll
  for (int jt = 0; jt < 4; ++jt)
    #pragma unroll
    for (int i = 0; i < 4; ++i) {
      int j = jt * 16 + quad * 4 + i; if (j > 48) j = 48;
      bj4[jt][i] = (j / 7) * 13 + (j % 7);
    }

  // ---- S^T accumulators, bias as C-in ----
  f32x4 sacc[4][4];  // [jt][rt]
  #pragma unroll
  for (int jt = 0; jt < 4; ++jt)
    #pragma unroll
    for (int rt = 0; rt < 4; ++rt)
      #pragma unroll
      for (int i = 0; i < 4; ++i)
        sacc[jt][rt][i] = biasW[bi[rt] - bj4[jt][i]];

  // ---- K / Q fragments straight from global ----
  bf16x8 kf[4], qf[4];
  const bf16x8 zf = {};
  #pragma unroll
  for (int jt = 0; jt < 4; ++jt) {
    int t = jt * 16 + m15; if (t > 48) t = 48;
    long row = rowbase + (t / 7) * 112 + (t % 7);
    kf[jt] = *(const bf16x8*)(qkv_u + row * 576 + 192 + h * 24 + quad * 8);
    if (quad == 3) kf[jt] = zf;   // zero d=24..31 pad (one side zero -> ok)
  }
  #pragma unroll
  for (int rt = 0; rt < 4; ++rt) {
    int t = rt * 16 + m15; if (t > 48) t = 48;
    long row = rowbase + (t / 7) * 112 + (t % 7);
    qf[rt] = *(const bf16x8*)(qkv_u + row * 576 + h * 24 + quad * 8);
  }
  #pragma unroll
  for (int jt = 0; jt < 4; ++jt)
    #pragma unroll
    for (int rt = 0; rt < 4; ++rt)
      sacc[jt][rt] = __builtin_amdgcn_mfma_f32_16x16x32_bf16(
          kf[jt], qf[rt], sacc[jt][rt], 0, 0, 0);

  // ---- mask j >= 49 (jt=3: j = 48 + quad*4 + i) ----
  #pragma unroll
  for (int rt = 0; rt < 4; ++rt) {
    if (quad != 0) sacc[3][rt][0] = -1e30f;
    sacc[3][rt][1] = -1e30f;
    sacc[3][rt][2] = -1e30f;
    sacc[3][rt][3] = -1e30f;
  }

  // ---- softmax over j per r-column (unnormalized; inv kept per rt) ----
  float inv[4];
  #pragma unroll
  for (int rt = 0; rt < 4; ++rt) {
    float mx = sacc[0][rt][0];
    #pragma unroll
    for (int jt = 0; jt < 4; ++jt)
      #pragma unroll
      for (int i = 0; i < 4; ++i)
        mx = fmaxf(mx, sacc[jt][rt][i]);
    mx = fmaxf(mx, __shfl_xor(mx, 16, 64));
    mx = fmaxf(mx, __shfl_xor(mx, 32, 64));
    float sum = 0.f;
    #pragma unroll
    for (int jt = 0; jt < 4; ++jt)
      #pragma unroll
      for (int i = 0; i < 4; ++i) {
        float p = __expf(sacc[jt][rt][i] - mx);
        sacc[jt][rt][i] = p;
        sum += p;
      }
    sum += __shfl_xor(sum, 16, 64);
    sum += __shfl_xor(sum, 32, 64);
    inv[rt] = 1.f / sum;
  }

  // ---- P -> bf16 -> swizzled LDS ([64 r][64 j], byte ^= (m15&7)<<4) ----
  const int swzP = (m15 & 7) << 4;
  #pragma unroll
  for (int rt = 0; rt < 4; ++rt)
    #pragma unroll
    for (int jt = 0; jt < 4; ++jt)
      #pragma unroll
      for (int u = 0; u < 2; ++u) {
        unsigned pk;
        asm("v_cvt_pk_bf16_f32 %0, %1, %2"
            : "=v"(pk)
            : "v"(sacc[jt][rt][2 * u]), "v"(sacc[jt][rt][2 * u + 1]));
        int j0 = jt * 16 + quad * 4 + 2 * u;
        int lin = (rt * 16 + m15) * 128 + j0 * 2;
        *(unsigned*)(Pb + (lin ^ swzP)) = pk;
      }

  // ---- O = P.V ----
  f32x4 oacc[4][2];
  #pragma unroll
  for (int mt = 0; mt < 4; ++mt)
    #pragma unroll
    for (int nt = 0; nt < 2; ++nt) oacc[mt][nt] = (f32x4){0.f, 0.f, 0.f, 0.f};

  #pragma unroll
  for (int kt = 0; kt < 2; ++kt) {
    bf16x8 pf[4];
    #pragma unroll
    for (int mt = 0; mt < 4; ++mt) {
      int lin = (mt * 16 + m15) * 128 + kt * 64 + quad * 16;
      pf[mt] = *(const bf16x8*)(Pb + (lin ^ swzP));
    }
    bf16x8 vf[2];
    #pragma unroll
    for (int nt = 0; nt < 2; ++nt) {
      u32x4 w;
      #pragma unroll
      for (int e2 = 0; e2 < 4; ++e2) {
        int j_lo = kt * 32 + quad * 8 + 2 * e2;
        int lin_lo = j_lo * 64 + (nt * 16 + m15) * 2;
        int lin_hi = lin_lo + 64;
        unsigned lo = *(const ushort*)(Vb + (lin_lo ^ (quad << 5)));
        unsigned hi = *(const ushort*)(Vb + (lin_hi ^ (quad << 5)));
        w[e2] = lo | (hi << 16);
      }
      vf[nt] = __builtin_bit_cast(bf16x8, w);
    }
    #pragma unroll
    for (int mt = 0; mt < 4; ++mt)
      #pragma unroll
      for (int nt = 0; nt < 2; ++nt)
        oacc[mt][nt] = __builtin_amdgcn_mfma_f32_16x16x32_bf16(
            pf[mt], vf[nt], oacc[mt][nt], 0, 0, 0);
  }

  // ---- normalize (redistribute inv via bpermute) + store ----
  #pragma unroll
  for (int mt = 0; mt < 4; ++mt)
    #pragma unroll
    for (int i = 0; i < 4; ++i) {
      float iv = __shfl(inv[mt], quad * 4 + i, 64);
      int r = mt * 16 + quad * 4 + i;
      if (r < 49) {
        long row = rowbase + (r / 7) * 112 + (r % 7);
        ushort* dst = qkv_u + row * 576 + h * 24;
        dst[m15] = f2bfu(oacc[mt][0][i] * iv);
        if (m15 < 8) dst[16 + m15] = f2bfu(oacc[mt][1][i] * iv);
      }
    }
}

// -------- depthwise 3x3 conv + bias + tanh-GELU, pipelined ring -------------
// Prev version was latency-bound (occupancy 19%, VALUBusy 53%, HBM 38%):
// loads of iteration m were consumed immediately by compute of m.  Now:
// 10-slot row ring, iteration m prefetches m+1's 4 rows BEFORE computing m
// (loads get a full compute phase to land); h-split 28->16 doubles the grid;
// channel-pair f32x2 accumulate -> v_pk_fma_f32 halves FMA issue;
// v_cvt_pk_bf16_f32 on the store path.  All ring indices compile-time.
// grid: (7 h-seg of 16, 56 w-pairs, CB images), 192 threads (= 768 ch / 4).
__global__ __launch_bounds__(192) void dwconv_gelu_kernel(
    const ushort* __restrict__ y1, const float* __restrict__ w,
    const float* __restrict__ bias, ushort* __restrict__ y2)
{
  const int c = threadIdx.x * 4;       // channel group
  const int w0 = blockIdx.y * 2;       // output cols w0, w0+1
  const int b = blockIdx.z;
  const int h0 = blockIdx.x * 16;

  f32x2 wt2[9][2];                     // per-tap, channel pairs
  #pragma unroll
  for (int k = 0; k < 9; ++k) {
    wt2[k][0] = (f32x2){w[(c + 0) * 9 + k], w[(c + 1) * 9 + k]};
    wt2[k][1] = (f32x2){w[(c + 2) * 9 + k], w[(c + 3) * 9 + k]};
  }
  f32x2 bs2[2] = {(f32x2){bias[c], bias[c + 1]},
                  (f32x2){bias[c + 2], bias[c + 3]}};

  const bool okL = (w0 > 0), okR = (w0 + 2 < 112);
  uint2 rb[10][4];   // row ring: cols w0-1..w0+2, 4 ch packed as 2 u32

  auto loadrow = [&](int h, uint2 dst[4]) {
    const uint2 z = {0u, 0u};
    if (h < 0 || h >= 112) {
      dst[0] = z; dst[1] = z; dst[2] = z; dst[3] = z;
      return;
    }
    const ushort* p = y1 + (((size_t)(b * 112 + h)) * 112 + w0) * HID + c;
    dst[0] = okL ? *(const uint2*)(p - HID) : z;
    dst[1] = *(const uint2*)(p);
    dst[2] = *(const uint2*)(p + HID);
    dst[3] = okR ? *(const uint2*)(p + 2 * HID) : z;
  };

  // preload slots 0..5 = rows h0-1 .. h0+4
  #pragma unroll
  for (int s = 0; s < 6; ++s) loadrow(h0 - 1 + s, rb[s]);

  #pragma unroll
  for (int m = 0; m < 4; ++m) {
    // prefetch m+1's rows (h0+4m+5 .. +8) into slots (4m+6..4m+9)%10
    if (m < 3) {
      #pragma unroll
      for (int k = 0; k < 4; ++k)
        loadrow(h0 + 4 * m + 5 + k, rb[(4 * m + 6 + k) % 10]);
    }
    #pragma unroll
    for (int o = 0; o < 4; ++o) {
      f32x2 a0[2], a1[2];
      a0[0] = bs2[0]; a0[1] = bs2[1];
      a1[0] = bs2[0]; a1[1] = bs2[1];
      #pragma unroll
      for (int dy = 0; dy < 3; ++dy) {
        const int s = (4 * m + o + dy) % 10;
        f32x2 col[4][2];
        #pragma unroll
        for (int x = 0; x < 4; ++x) {
          unsigned lo = rb[s][x].x, hi = rb[s][x].y;
          col[x][0] = (f32x2){__uint_as_float(lo << 16),
                              __uint_as_float(lo & 0xffff0000u)};
          col[x][1] = (f32x2){__uint_as_float(hi << 16),
                              __uint_as_float(hi & 0xffff0000u)};
        }
        #pragma unroll
        for (int dx = 0; dx < 3; ++dx)
          #pragma unroll
          for (int p = 0; p < 2; ++p) {
            a0[p] += wt2[dy * 3 + dx][p] * col[dx][p];
            a1[p] += wt2[dy * 3 + dx][p] * col[dx + 1][p];
          }
      }
      ushort* outp = y2 + (((size_t)(b * 112 + h0 + 4 * m + o)) * 112 + w0) * HID + c;
      unsigned p0, p1, p2, p3;
      {
        float g0 = fgelu(a0[0][0]), g1 = fgelu(a0[0][1]);
        float g2 = fgelu(a0[1][0]), g3 = fgelu(a0[1][1]);
        asm("v_cvt_pk_bf16_f32 %0, %1, %2" : "=v"(p0) : "v"(g0), "v"(g1));
        asm("v_cvt_pk_bf16_f32 %0, %1, %2" : "=v"(p1) : "v"(g2), "v"(g3));
        float h0f = fgelu(a1[0][0]), h1f = fgelu(a1[0][1]);
        float h2f = fgelu(a1[1][0]), h3f = fgelu(a1[1][1]);
        asm("v_cvt_pk_bf16_f32 %0, %1, %2" : "=v"(p2) : "v"(h0f), "v"(h1f));
        asm("v_cvt_pk_bf16_f32 %0, %1, %2" : "=v"(p3) : "v"(h2f), "v"(h3f));
      }
      *(uint2*)(outp) = (uint2){p0, p1};
      *(uint2*)(outp + HID) = (uint2){p2, p3};
    }
  }
}

// ---------------------------------------------------------------------------
extern "C" void kernel_launch(void* const* d_in, const int* in_sizes, int n_in,
                              void* d_out, int out_size, void* d_ws, size_t ws_size,
                              hipStream_t stream) {
  const float* x      = (const float*)d_in[0];
  const float* n1g    = (const float*)d_in[1];
  const float* n1b    = (const float*)d_in[2];
  const float* q_w    = (const float*)d_in[3];
  const float* q_b    = (const float*)d_in[4];
  const float* kv_w   = (const float*)d_in[5];
  const float* kv_b   = (const float*)d_in[6];
  const float* rpe    = (const float*)d_in[7];
  const float* proj_w = (const float*)d_in[8];
  const float* proj_b = (const float*)d_in[9];
  const float* n2g    = (const float*)d_in[10];
  const float* n2b    = (const float*)d_in[11];
  const float* fc1_w  = (const float*)d_in[12];
  const float* fc1_b  = (const float*)d_in[13];
  const float* dw_w   = (const float*)d_in[14];
  const float* dw_b   = (const float*)d_in[15];
  const float* fc2_w  = (const float*)d_in[16];
  const float* fc2_b  = (const float*)d_in[17];
  float* out = (float*)d_out;

  // ---- weights at front of ws (~0.9 MB) ----
  char* ws = (char*)d_ws;
  __hip_bfloat16* wcat  = (__hip_bfloat16*)(ws);               // 576*192 bf16
  __hip_bfloat16* projw = (__hip_bfloat16*)(ws + 221184);      // 192*192
  __hip_bfloat16* fc1w  = (__hip_bfloat16*)(ws + 294912);      // 768*192
  __hip_bfloat16* fc2w  = (__hip_bfloat16*)(ws + 589824);      // 192*768
  float* bcat           = (float*)(ws + 884736);               // 576 f32
  const size_t WOFF = 1u << 20;                                // 1 MB

  // ---- pick images-per-chunk CB so the activation buffers fit ws_size ----
  int CB = 8;
  while (CB > 1 && WOFF + (size_t)CB * 12544 * 3456 > ws_size) CB >>= 1;
  const size_t Mc = (size_t)CB * 12544;
  char* Abuf = ws + WOFF;                        // xn / yn   (bf16 Mc x 192)
  char* Bbuf = Abuf + Mc * 384;                  // qkv (Mc x 576) / y2 (Mc x 768)
  char* Cbuf = Bbuf + Mc * 1536;                 // y1 (bf16 Mc x 768)
  __hip_bfloat16* xn  = (__hip_bfloat16*)Abuf;
  __hip_bfloat16* qkv = (__hip_bfloat16*)Bbuf;
  __hip_bfloat16* y2  = (__hip_bfloat16*)Bbuf;
  __hip_bfloat16* y1  = (__hip_bfloat16*)Cbuf;

  prep_kernel<<<576, 256, 0, stream>>>(q_w, q_b, kv_w, kv_b, proj_w, fc1_w,
                                       fc2_w, wcat, bcat, projw, fc1w, fc2w);

  const int nChunks = 8 / CB;
  const int mt = CB * 98;
  for (int cchunk = 0; cchunk < nChunks; ++cchunk) {
    const size_t toff = (size_t)cchunk * Mc;
    const float* xc = x + toff * C_DIM;
    float* oc = out + toff * C_DIM;

    ln_kernel<<<(int)(Mc / 4), 256, 0, stream>>>(xc, n1g, n1b, xn);
    gemmA_kernel<0><<<dim3(1, mt), 512, 0, stream>>>(
        (const ushort*)xn, 192, (const ushort*)wcat, bcat, nullptr, qkv, 576);
    attn_kernel<<<CB * 512, 256, 0, stream>>>(rpe, qkv);
    gemmA_ln_kernel<<<dim3(1, mt), 512, 0, stream>>>(
        (const ushort*)qkv, 576, (const ushort*)projw, proj_b, xc, oc,
        n2g, n2b, xn);
    gemmA_kernel<0><<<dim3(1, mt), 512, 0, stream>>>(
        (const ushort*)xn, 192, (const ushort*)fc1w, fc1_b, nullptr, y1, 768);
    dwconv_gelu_kernel<<<dim3(7, 56, CB), 192, 0, stream>>>(
        (const ushort*)y1, dw_w, dw_b, (ushort*)y2);
    gemmB_kernel<<<dim3(1, mt), 512, 0, stream>>>(
        (const ushort*)y2, (const ushort*)fc2w, fc2_b, oc, oc);
  }
}

// Round 5
// 585.407 us; speedup vs baseline: 1.4050x; 1.0026x over previous
//
#include <hip/hip_runtime.h>
#include <hip/hip_bf16.h>
#include <cmath>

// Problem constants (B=8, H=W=112, C=192, heads=8, hd=24, ps=7, hid=768)
#define C_DIM 192
#define HID 768

typedef __attribute__((ext_vector_type(8))) __bf16 bf16x8;
typedef __attribute__((ext_vector_type(4))) float f32x4;
typedef __attribute__((ext_vector_type(2))) float f32x2;
typedef __attribute__((ext_vector_type(8))) unsigned short u16x8;
typedef __attribute__((ext_vector_type(4))) unsigned int u32x4;

__device__ __forceinline__ void gload_lds16(const void* g, void* l) {
  __builtin_amdgcn_global_load_lds(
      (__attribute__((address_space(1))) void*)(const_cast<void*>(g)),
      (__attribute__((address_space(3))) void*)(l), 16, 0, 0);
}

__device__ __forceinline__ float bfu2f(ushort u) {
  return __uint_as_float((unsigned)u << 16);
}
__device__ __forceinline__ ushort f2bfu(float f) {
  __hip_bfloat16 h = __float2bfloat16(f);
  return *reinterpret_cast<ushort*>(&h);
}
// tanh-form GELU: |err| ~3e-4 << bf16 ulp (validated R5, absmax 0.0156)
__device__ __forceinline__ float fgelu(float x) {
  float z = x * (1.5957691216f + 0.071354816f * x * x);
  return x / (1.f + __expf(-z));
}

// ---------------- prep: weights fp32 -> bf16 (+ fold q scale) ----------------
__global__ __launch_bounds__(256) void prep_kernel(
    const float* __restrict__ q_w, const float* __restrict__ q_b,
    const float* __restrict__ kv_w, const float* __restrict__ kv_b,
    const float* __restrict__ proj_w, const float* __restrict__ fc1_w,
    const float* __restrict__ fc2_w,
    __hip_bfloat16* __restrict__ wcat, float* __restrict__ bcat,
    __hip_bfloat16* __restrict__ projw, __hip_bfloat16* __restrict__ fc1w,
    __hip_bfloat16* __restrict__ fc2w)
{
  int idx = blockIdx.x * 256 + threadIdx.x;
  const float scale = 0.20412414523193154f;  // 24^-0.5
  if (idx < 110592) {
    float v = (idx < 36864) ? q_w[idx] * scale : kv_w[idx - 36864];
    wcat[idx] = __float2bfloat16(v);
  }
  if (idx < 576) bcat[idx] = (idx < 192) ? q_b[idx] * scale : kv_b[idx - 192];
  if (idx < 36864) projw[idx] = __float2bfloat16(proj_w[idx]);
  if (idx < 147456) {
    fc1w[idx] = __float2bfloat16(fc1_w[idx]);
    fc2w[idx] = __float2bfloat16(fc2_w[idx]);
  }
}

// -------- LayerNorm fp32 -> bf16, one wave per token (192 = 64*3) -----------
__global__ __launch_bounds__(256) void ln_kernel(
    const float* __restrict__ x, const float* __restrict__ g,
    const float* __restrict__ b, __hip_bfloat16* __restrict__ out)
{
  int t = blockIdx.x * 4 + (threadIdx.x >> 6);
  int lane = threadIdx.x & 63;
  const float* xr = x + (size_t)t * C_DIM;
  float v0 = xr[lane], v1 = xr[lane + 64], v2 = xr[lane + 128];
  float s = v0 + v1 + v2;
  float sq = v0 * v0 + v1 * v1 + v2 * v2;
  #pragma unroll
  for (int off = 32; off > 0; off >>= 1) {
    s += __shfl_xor(s, off, 64);
    sq += __shfl_xor(sq, off, 64);
  }
  float mean = s * (1.0f / 192.0f);
  float var = sq * (1.0f / 192.0f) - mean * mean;
  float rstd = rsqrtf(var + 1e-5f);
  size_t o = (size_t)t * C_DIM;
  out[o + lane]       = __float2bfloat16((v0 - mean) * rstd * g[lane] + b[lane]);
  out[o + lane + 64]  = __float2bfloat16((v1 - mean) * rstd * g[lane + 64] + b[lane + 64]);
  out[o + lane + 128] = __float2bfloat16((v2 - mean) * rstd * g[lane + 128] + b[lane + 128]);
}

// ===== GEMM variant A: K=192, A-tile LDS-resident, serial n-tiles ===========
template <int EPI>
__global__ __launch_bounds__(512, 4) void gemmA_kernel(
    const ushort* __restrict__ X, int lda, const ushort* __restrict__ W,
    const float* __restrict__ bias, const float* __restrict__ addin,
    void* __restrict__ outp, int N)
{
  __shared__ __align__(16) ushort Al[128 * 192];  // 49152 B
  __shared__ __align__(16) ushort Bl[64 * 192];   // 24576 B
  const int tid = threadIdx.x;
  const int wv = tid >> 6;          // 0..7
  const int lane = tid & 63;
  const int quad = lane >> 4;
  const int m15 = lane & 15;
  const long mBase = (long)blockIdx.y * 128;
  const int NT = N >> 6;

  #pragma unroll
  for (int r = 0; r < 6; ++r) {
    int sI = tid + r * 512;
    int row = sI / 24;
    int cs = sI - row * 24;
    int gc = cs - (row % 24); if (gc < 0) gc += 24;
    gload_lds16(X + (mBase + row) * (long)lda + gc * 8, Al + sI * 8);
  }

  const int rA0 = wv * 16 + m15;
  const int rA0m = rA0 % 24;

  for (int nt = 0; nt < NT; ++nt) {
    __syncthreads();
    #pragma unroll
    for (int r = 0; r < 3; ++r) {
      int sI = tid + r * 512;
      int row = sI / 24;
      int cs = sI - row * 24;
      int gc = cs - (row % 24); if (gc < 0) gc += 24;
      gload_lds16(W + (long)(nt * 64 + row) * 192 + gc * 8, Bl + sI * 8);
    }
    __syncthreads();

    f32x4 acc[4];
    #pragma unroll
    for (int c = 0; c < 4; ++c) acc[c] = (f32x4){0.f, 0.f, 0.f, 0.f};

    #pragma unroll
    for (int ks = 0; ks < 6; ++ks) {
      const int l = ks * 4 + quad;
      int pa0 = l + rA0m; if (pa0 >= 24) pa0 -= 24;
      bf16x8 a0 = *(const bf16x8*)&Al[rA0 * 192 + pa0 * 8];
      #pragma unroll
      for (int ct = 0; ct < 4; ++ct) {
        const int rB = ct * 16 + m15;
        int pb = l + (rB % 24); if (pb >= 24) pb -= 24;
        bf16x8 b = *(const bf16x8*)&Bl[rB * 192 + pb * 8];
        acc[ct] = __builtin_amdgcn_mfma_f32_16x16x32_bf16(a0, b, acc[ct], 0, 0, 0);
      }
    }
    #pragma unroll
    for (int ct = 0; ct < 4; ++ct)
      #pragma unroll
      for (int i = 0; i < 4; ++i) {
        long row = mBase + wv * 16 + quad * 4 + i;
        int col = nt * 64 + ct * 16 + m15;
        float v = acc[ct][i] + bias[col];
        if (EPI == 1) {
          v += addin[row * N + col];
          ((float*)outp)[row * N + col] = v;
        } else {
          ((__hip_bfloat16*)outp)[row * N + col] = __float2bfloat16(v);
        }
      }
  }
}

// ===== GEMM variant A+LN: proj with residual add, f32 out, fused LN ========
__global__ __launch_bounds__(512, 4) void gemmA_ln_kernel(
    const ushort* __restrict__ X, int lda, const ushort* __restrict__ W,
    const float* __restrict__ bias, const float* __restrict__ addin,
    float* __restrict__ outp, const float* __restrict__ lng,
    const float* __restrict__ lnb, __hip_bfloat16* __restrict__ xnout)
{
  __shared__ __align__(16) ushort Al[128 * 192];
  __shared__ __align__(16) ushort Bl[64 * 192];
  const int tid = threadIdx.x;
  const int wv = tid >> 6;
  const int lane = tid & 63;
  const int quad = lane >> 4;
  const int m15 = lane & 15;
  const long mBase = (long)blockIdx.y * 128;

  #pragma unroll
  for (int r = 0; r < 6; ++r) {
    int sI = tid + r * 512;
    int row = sI / 24;
    int cs = sI - row * 24;
    int gc = cs - (row % 24); if (gc < 0) gc += 24;
    gload_lds16(X + (mBase + row) * (long)lda + gc * 8, Al + sI * 8);
  }

  const int rA0 = wv * 16 + m15;
  const int rA0m = rA0 % 24;

  f32x4 acc[3][4];
  #pragma unroll
  for (int n = 0; n < 3; ++n)
    #pragma unroll
    for (int c = 0; c < 4; ++c) acc[n][c] = (f32x4){0.f, 0.f, 0.f, 0.f};

  #pragma unroll
  for (int nt = 0; nt < 3; ++nt) {
    __syncthreads();
    #pragma unroll
    for (int r = 0; r < 3; ++r) {
      int sI = tid + r * 512;
      int row = sI / 24;
      int cs = sI - row * 24;
      int gc = cs - (row % 24); if (gc < 0) gc += 24;
      gload_lds16(W + (long)(nt * 64 + row) * 192 + gc * 8, Bl + sI * 8);
    }
    __syncthreads();
    #pragma unroll
    for (int ks = 0; ks < 6; ++ks) {
      const int l = ks * 4 + quad;
      int pa0 = l + rA0m; if (pa0 >= 24) pa0 -= 24;
      bf16x8 a0 = *(const bf16x8*)&Al[rA0 * 192 + pa0 * 8];
      #pragma unroll
      for (int ct = 0; ct < 4; ++ct) {
        const int rB = ct * 16 + m15;
        int pb = l + (rB % 24); if (pb >= 24) pb -= 24;
        bf16x8 b = *(const bf16x8*)&Bl[rB * 192 + pb * 8];
        acc[nt][ct] = __builtin_amdgcn_mfma_f32_16x16x32_bf16(a0, b, acc[nt][ct], 0, 0, 0);
      }
    }
  }

  float sum_[4], sq_[4];
  #pragma unroll
  for (int i = 0; i < 4; ++i) { sum_[i] = 0.f; sq_[i] = 0.f; }

  #pragma unroll
  for (int nt = 0; nt < 3; ++nt)
    #pragma unroll
    for (int ct = 0; ct < 4; ++ct) {
      int col = nt * 64 + ct * 16 + m15;
      float cb = bias[col];
      #pragma unroll
      for (int i = 0; i < 4; ++i) {
        long row = mBase + wv * 16 + quad * 4 + i;
        float v = acc[nt][ct][i] + cb + addin[row * 192 + col];
        outp[row * 192 + col] = v;
        acc[nt][ct][i] = v;
        sum_[i] += v;
        sq_[i] += v * v;
      }
    }

  float mean_[4], rstd_[4];
  #pragma unroll
  for (int i = 0; i < 4; ++i) {
    float s = sum_[i], q = sq_[i];
    #pragma unroll
    for (int m = 1; m < 16; m <<= 1) {
      s += __shfl_xor(s, m, 64);
      q += __shfl_xor(q, m, 64);
    }
    float mean = s * (1.0f / 192.0f);
    mean_[i] = mean;
    rstd_[i] = rsqrtf(q * (1.0f / 192.0f) - mean * mean + 1e-5f);
  }

  #pragma unroll
  for (int nt = 0; nt < 3; ++nt)
    #pragma unroll
    for (int ct = 0; ct < 4; ++ct) {
      int col = nt * 64 + ct * 16 + m15;
      float cg = lng[col], cbb = lnb[col];
      #pragma unroll
      for (int i = 0; i < 4; ++i) {
        long row = mBase + wv * 16 + quad * 4 + i;
        float v = (acc[nt][ct][i] - mean_[i]) * rstd_[i] * cg + cbb;
        xnout[row * 192 + col] = __float2bfloat16(v);
      }
    }
}

// ===== GEMM variant B: fc2 (K=768, N=192). 4 K-chunks, 3 live n-tile accs ==
__global__ __launch_bounds__(512, 4) void gemmB_kernel(
    const ushort* __restrict__ X, const ushort* __restrict__ W,
    const float* __restrict__ bias, const float* __restrict__ addin,
    float* __restrict__ outp)
{
  __shared__ __align__(16) ushort Al[128 * 192];
  __shared__ __align__(16) ushort Bl[64 * 192];
  const int tid = threadIdx.x;
  const int wv = tid >> 6;
  const int lane = tid & 63;
  const int quad = lane >> 4;
  const int m15 = lane & 15;
  const long mBase = (long)blockIdx.y * 128;

  const int rA0 = wv * 16 + m15;
  const int rA0m = rA0 % 24;

  f32x4 acc[3][4];
  #pragma unroll
  for (int n = 0; n < 3; ++n)
    #pragma unroll
    for (int c = 0; c < 4; ++c) acc[n][c] = (f32x4){0.f, 0.f, 0.f, 0.f};

  for (int kc = 0; kc < 4; ++kc) {
    for (int nt = 0; nt < 3; ++nt) {
      __syncthreads();
      if (nt == 0) {
        #pragma unroll
        for (int r = 0; r < 6; ++r) {
          int sI = tid + r * 512;
          int row = sI / 24;
          int cs = sI - row * 24;
          int gc = cs - (row % 24); if (gc < 0) gc += 24;
          gload_lds16(X + (mBase + row) * 768l + kc * 192 + gc * 8, Al + sI * 8);
        }
      }
      #pragma unroll
      for (int r = 0; r < 3; ++r) {
        int sI = tid + r * 512;
        int row = sI / 24;
        int cs = sI - row * 24;
        int gc = cs - (row % 24); if (gc < 0) gc += 24;
        gload_lds16(W + (long)(nt * 64 + row) * 768 + kc * 192 + gc * 8, Bl + sI * 8);
      }
      __syncthreads();
      #pragma unroll
      for (int ks = 0; ks < 6; ++ks) {
        const int l = ks * 4 + quad;
        int pa0 = l + rA0m; if (pa0 >= 24) pa0 -= 24;
        bf16x8 a0 = *(const bf16x8*)&Al[rA0 * 192 + pa0 * 8];
        #pragma unroll
        for (int ct = 0; ct < 4; ++ct) {
          const int rB = ct * 16 + m15;
          int pb = l + (rB % 24); if (pb >= 24) pb -= 24;
          bf16x8 b = *(const bf16x8*)&Bl[rB * 192 + pb * 8];
          acc[nt][ct] = __builtin_amdgcn_mfma_f32_16x16x32_bf16(a0, b, acc[nt][ct], 0, 0, 0);
        }
      }
    }
  }
  #pragma unroll
  for (int nt = 0; nt < 3; ++nt)
    #pragma unroll
    for (int ct = 0; ct < 4; ++ct)
      #pragma unroll
      for (int i = 0; i < 4; ++i) {
        long row = mBase + wv * 16 + quad * 4 + i;
        int col = nt * 64 + ct * 16 + m15;
        float v = acc[nt][ct][i] + bias[col] + addin[row * 192 + col];
        outp[row * 192 + col] = v;
      }
}

// ============ window attention: MFMA version, one wave per window-head ======
__global__ __launch_bounds__(256, 3) void attn_kernel(
    const float* __restrict__ rpe, __hip_bfloat16* __restrict__ qkv)
{
  __shared__ __align__(16) char smem[51968];
  const int tid = threadIdx.x;
  const int lane = tid & 63;
  const int wv = tid >> 6;
  const int quad = lane >> 4;
  const int m15 = lane & 15;
  const int wh = blockIdx.x * 4 + wv;
  const int h = wh & 7;
  const int win = wh >> 3;
  const int b = win >> 8;
  const int wl = win & 255;
  const int whi = wl >> 4;
  const int wwi = wl & 15;
  ushort* qkv_u = (ushort*)qkv;
  char* Vb = smem + wv * 4096;                       // V: [64 j][32 d] bf16
  char* Pb = smem + 16384 + wv * 8192;               // P: [64 r][64 j] bf16
  float* biasW = (float*)(smem + 49152 + wv * 704);  // 169 f32

  const long rowbase = (long)b * 12544 + (long)(whi * 7) * 112 + wwi * 7;

  // ---- stage V rows (swizzled) ; zero pad rows 49..63 (K-dim safety) ----
  {
    int j = lane;
    int f = ((j >> 3) & 3) << 5;
    if (j < 49) {
      int py = j / 7, px = j - py * 7;
      long row = rowbase + py * 112 + px;
      const ushort* src = qkv_u + row * 576 + 384 + h * 24;
      #pragma unroll
      for (int c = 0; c < 3; ++c) {
        u16x8 val = *(const u16x8*)(src + c * 8);
        *(u16x8*)(Vb + ((j * 64 + c * 16) ^ f)) = val;
      }
    } else {
      u16x8 z = {};
      #pragma unroll
      for (int c = 0; c < 4; ++c)
        *(u16x8*)(Vb + ((j * 64 + c * 16) ^ f)) = z;
    }
  }
  for (int r = lane; r < 169; r += 64) biasW[r] = rpe[r * 8 + h];

  // ---- relative-position index components ----
  int bi[4];
  #pragma unroll
  for (int rt = 0; rt < 4; ++rt) {
    int r = rt * 16 + m15; if (r > 48) r = 48;
    bi[rt] = (r / 7) * 13 + (r % 7) + 84;
  }
  int bj4[4][4];
  #pragma unroll
  for (int jt = 0; jt < 4; ++jt)
    #pragma unroll
    for (int i = 0; i < 4; ++i) {
      int j = jt * 16 + quad * 4 + i; if (j > 48) j = 48;
      bj4[jt][i] = (j / 7) * 13 + (j % 7);
    }

  // ---- S^T accumulators, bias as C-in ----
  f32x4 sacc[4][4];  // [jt][rt]
  #pragma unroll
  for (int jt = 0; jt < 4; ++jt)
    #pragma unroll
    for (int rt = 0; rt < 4; ++rt)
      #pragma unroll
      for (int i = 0; i < 4; ++i)
        sacc[jt][rt][i] = biasW[bi[rt] - bj4[jt][i]];

  // ---- K / Q fragments straight from global ----
  bf16x8 kf[4], qf[4];
  const bf16x8 zf = {};
  #pragma unroll
  for (int jt = 0; jt < 4; ++jt) {
    int t = jt * 16 + m15; if (t > 48) t = 48;
    long row = rowbase + (t / 7) * 112 + (t % 7);
    kf[jt] = *(const bf16x8*)(qkv_u + row * 576 + 192 + h * 24 + quad * 8);
    if (quad == 3) kf[jt] = zf;   // zero d=24..31 pad (one side zero -> ok)
  }
  #pragma unroll
  for (int rt = 0; rt < 4; ++rt) {
    int t = rt * 16 + m15; if (t > 48) t = 48;
    long row = rowbase + (t / 7) * 112 + (t % 7);
    qf[rt] = *(const bf16x8*)(qkv_u + row * 576 + h * 24 + quad * 8);
  }
  #pragma unroll
  for (int jt = 0; jt < 4; ++jt)
    #pragma unroll
    for (int rt = 0; rt < 4; ++rt)
      sacc[jt][rt] = __builtin_amdgcn_mfma_f32_16x16x32_bf16(
          kf[jt], qf[rt], sacc[jt][rt], 0, 0, 0);

  // ---- mask j >= 49 (jt=3: j = 48 + quad*4 + i) ----
  #pragma unroll
  for (int rt = 0; rt < 4; ++rt) {
    if (quad != 0) sacc[3][rt][0] = -1e30f;
    sacc[3][rt][1] = -1e30f;
    sacc[3][rt][2] = -1e30f;
    sacc[3][rt][3] = -1e30f;
  }

  // ---- softmax over j per r-column (unnormalized; inv kept per rt) ----
  float inv[4];
  #pragma unroll
  for (int rt = 0; rt < 4; ++rt) {
    float mx = sacc[0][rt][0];
    #pragma unroll
    for (int jt = 0; jt < 4; ++jt)
      #pragma unroll
      for (int i = 0; i < 4; ++i)
        mx = fmaxf(mx, sacc[jt][rt][i]);
    mx = fmaxf(mx, __shfl_xor(mx, 16, 64));
    mx = fmaxf(mx, __shfl_xor(mx, 32, 64));
    float sum = 0.f;
    #pragma unroll
    for (int jt = 0; jt < 4; ++jt)
      #pragma unroll
      for (int i = 0; i < 4; ++i) {
        float p = __expf(sacc[jt][rt][i] - mx);
        sacc[jt][rt][i] = p;
        sum += p;
      }
    sum += __shfl_xor(sum, 16, 64);
    sum += __shfl_xor(sum, 32, 64);
    inv[rt] = 1.f / sum;
  }

  // ---- P -> bf16 -> swizzled LDS ([64 r][64 j], byte ^= (m15&7)<<4) ----
  const int swzP = (m15 & 7) << 4;
  #pragma unroll
  for (int rt = 0; rt < 4; ++rt)
    #pragma unroll
    for (int jt = 0; jt < 4; ++jt)
      #pragma unroll
      for (int u = 0; u < 2; ++u) {
        unsigned pk;
        asm("v_cvt_pk_bf16_f32 %0, %1, %2"
            : "=v"(pk)
            : "v"(sacc[jt][rt][2 * u]), "v"(sacc[jt][rt][2 * u + 1]));
        int j0 = jt * 16 + quad * 4 + 2 * u;
        int lin = (rt * 16 + m15) * 128 + j0 * 2;
        *(unsigned*)(Pb + (lin ^ swzP)) = pk;
      }

  // ---- O = P.V ----
  f32x4 oacc[4][2];
  #pragma unroll
  for (int mt = 0; mt < 4; ++mt)
    #pragma unroll
    for (int nt = 0; nt < 2; ++nt) oacc[mt][nt] = (f32x4){0.f, 0.f, 0.f, 0.f};

  #pragma unroll
  for (int kt = 0; kt < 2; ++kt) {
    bf16x8 pf[4];
    #pragma unroll
    for (int mt = 0; mt < 4; ++mt) {
      int lin = (mt * 16 + m15) * 128 + kt * 64 + quad * 16;
      pf[mt] = *(const bf16x8*)(Pb + (lin ^ swzP));
    }
    bf16x8 vf[2];
    #pragma unroll
    for (int nt = 0; nt < 2; ++nt) {
      u32x4 w;
      #pragma unroll
      for (int e2 = 0; e2 < 4; ++e2) {
        int j_lo = kt * 32 + quad * 8 + 2 * e2;
        int lin_lo = j_lo * 64 + (nt * 16 + m15) * 2;
        int lin_hi = lin_lo + 64;
        unsigned lo = *(const ushort*)(Vb + (lin_lo ^ (quad << 5)));
        unsigned hi = *(const ushort*)(Vb + (lin_hi ^ (quad << 5)));
        w[e2] = lo | (hi << 16);
      }
      vf[nt] = __builtin_bit_cast(bf16x8, w);
    }
    #pragma unroll
    for (int mt = 0; mt < 4; ++mt)
      #pragma unroll
      for (int nt = 0; nt < 2; ++nt)
        oacc[mt][nt] = __builtin_amdgcn_mfma_f32_16x16x32_bf16(
            pf[mt], vf[nt], oacc[mt][nt], 0, 0, 0);
  }

  // ---- normalize (redistribute inv via bpermute) + store ----
  #pragma unroll
  for (int mt = 0; mt < 4; ++mt)
    #pragma unroll
    for (int i = 0; i < 4; ++i) {
      float iv = __shfl(inv[mt], quad * 4 + i, 64);
      int r = mt * 16 + quad * 4 + i;
      if (r < 49) {
        long row = rowbase + (r / 7) * 112 + (r % 7);
        ushort* dst = qkv_u + row * 576 + h * 24;
        dst[m15] = f2bfu(oacc[mt][0][i] * iv);
        if (m15 < 8) dst[16 + m15] = f2bfu(oacc[mt][1][i] * iv);
      }
    }
}

// -------- depthwise 3x3 conv + bias + tanh-GELU, low-VGPR sliding window ----
// R4's 10-slot ring regressed 2x (occupancy 26%, HBM 20%): big register
// footprint + unrolled schedule.  Redesign for TLP: thread = 2 ch x 2 cols
// (wt f32x2[9]=18 regs, window rA..rD = 16 regs, named vars only -> no
// scratch), block = 384 thr covering all 768 ch, __launch_bounds__(384,8)
// pins VGPR <= 64 -> 8 waves/SIMD eligible.  One row prefetched per iter
// (~2 iters of slack); #pragma unroll 4 renames the rotation.
// grid: (7 h-seg of 16, 56 w-pairs, CB images).
__global__ __launch_bounds__(384, 8) void dwconv_gelu_kernel(
    const ushort* __restrict__ y1, const float* __restrict__ w,
    const float* __restrict__ bias, ushort* __restrict__ y2)
{
  const int c = threadIdx.x * 2;       // channel pair
  const int w0 = blockIdx.y * 2;       // output cols w0, w0+1
  const int b = blockIdx.z;
  const int h0 = blockIdx.x * 16;

  f32x2 wt[9];
  #pragma unroll
  for (int k = 0; k < 9; ++k)
    wt[k] = (f32x2){w[(c + 0) * 9 + k], w[(c + 1) * 9 + k]};
  const f32x2 bs = (f32x2){bias[c], bias[c + 1]};

  const bool okL = (w0 > 0), okR = (w0 + 2 < 112);

  uint rA[4], rB[4], rC[4], rD[4];   // rows h-1,h,h+1,h+2; cols w0-1..w0+2

  auto loadrow = [&](int h, uint dst[4]) {
    if (h < 0 || h >= 112) {
      dst[0] = 0u; dst[1] = 0u; dst[2] = 0u; dst[3] = 0u;
      return;
    }
    const ushort* p = y1 + (((size_t)(b * 112 + h)) * 112 + w0) * HID + c;
    dst[0] = okL ? *(const uint*)(p - HID) : 0u;
    dst[1] = *(const uint*)(p);
    dst[2] = *(const uint*)(p + HID);
    dst[3] = okR ? *(const uint*)(p + 2 * HID) : 0u;
  };

  loadrow(h0 - 1, rA);
  loadrow(h0,     rB);
  loadrow(h0 + 1, rC);
  loadrow(h0 + 2, rD);

  auto accum = [&](const uint r[4], int dy, f32x2& a0, f32x2& a1) {
    f32x2 col[4];
    #pragma unroll
    for (int x = 0; x < 4; ++x)
      col[x] = (f32x2){__uint_as_float(r[x] << 16),
                       __uint_as_float(r[x] & 0xffff0000u)};
    #pragma unroll
    for (int dx = 0; dx < 3; ++dx) {
      a0 += wt[dy * 3 + dx] * col[dx];
      a1 += wt[dy * 3 + dx] * col[dx + 1];
    }
  };

  #pragma unroll 4
  for (int hh = 0; hh < 16; ++hh) {
    const int h = h0 + hh;
    f32x2 a0 = bs, a1 = bs;
    accum(rA, 0, a0, a1);
    accum(rB, 1, a0, a1);
    accum(rC, 2, a0, a1);

    ushort* outp = y2 + (((size_t)(b * 112 + h)) * 112 + w0) * HID + c;
    unsigned q0, q1;
    {
      float g0 = fgelu(a0[0]), g1 = fgelu(a0[1]);
      float g2 = fgelu(a1[0]), g3 = fgelu(a1[1]);
      asm("v_cvt_pk_bf16_f32 %0, %1, %2" : "=v"(q0) : "v"(g0), "v"(g1));
      asm("v_cvt_pk_bf16_f32 %0, %1, %2" : "=v"(q1) : "v"(g2), "v"(g3));
    }
    *(uint*)(outp) = q0;
    *(uint*)(outp + HID) = q1;

    // rotate window, prefetch row h+3 (consumed 2 iterations later)
    #pragma unroll
    for (int x = 0; x < 4; ++x) { rA[x] = rB[x]; rB[x] = rC[x]; rC[x] = rD[x]; }
    loadrow(h + 3, rD);
  }
}

// ---------------------------------------------------------------------------
extern "C" void kernel_launch(void* const* d_in, const int* in_sizes, int n_in,
                              void* d_out, int out_size, void* d_ws, size_t ws_size,
                              hipStream_t stream) {
  const float* x      = (const float*)d_in[0];
  const float* n1g    = (const float*)d_in[1];
  const float* n1b    = (const float*)d_in[2];
  const float* q_w    = (const float*)d_in[3];
  const float* q_b    = (const float*)d_in[4];
  const float* kv_w   = (const float*)d_in[5];
  const float* kv_b   = (const float*)d_in[6];
  const float* rpe    = (const float*)d_in[7];
  const float* proj_w = (const float*)d_in[8];
  const float* proj_b = (const float*)d_in[9];
  const float* n2g    = (const float*)d_in[10];
  const float* n2b    = (const float*)d_in[11];
  const float* fc1_w  = (const float*)d_in[12];
  const float* fc1_b  = (const float*)d_in[13];
  const float* dw_w   = (const float*)d_in[14];
  const float* dw_b   = (const float*)d_in[15];
  const float* fc2_w  = (const float*)d_in[16];
  const float* fc2_b  = (const float*)d_in[17];
  float* out = (float*)d_out;

  // ---- weights at front of ws (~0.9 MB) ----
  char* ws = (char*)d_ws;
  __hip_bfloat16* wcat  = (__hip_bfloat16*)(ws);               // 576*192 bf16
  __hip_bfloat16* projw = (__hip_bfloat16*)(ws + 221184);      // 192*192
  __hip_bfloat16* fc1w  = (__hip_bfloat16*)(ws + 294912);      // 768*192
  __hip_bfloat16* fc2w  = (__hip_bfloat16*)(ws + 589824);      // 192*768
  float* bcat           = (float*)(ws + 884736);               // 576 f32
  const size_t WOFF = 1u << 20;                                // 1 MB

  // ---- pick images-per-chunk CB so the activation buffers fit ws_size ----
  int CB = 8;
  while (CB > 1 && WOFF + (size_t)CB * 12544 * 3456 > ws_size) CB >>= 1;
  const size_t Mc = (size_t)CB * 12544;
  char* Abuf = ws + WOFF;                        // xn / yn   (bf16 Mc x 192)
  char* Bbuf = Abuf + Mc * 384;                  // qkv (Mc x 576) / y2 (Mc x 768)
  char* Cbuf = Bbuf + Mc * 1536;                 // y1 (bf16 Mc x 768)
  __hip_bfloat16* xn  = (__hip_bfloat16*)Abuf;
  __hip_bfloat16* qkv = (__hip_bfloat16*)Bbuf;
  __hip_bfloat16* y2  = (__hip_bfloat16*)Bbuf;
  __hip_bfloat16* y1  = (__hip_bfloat16*)Cbuf;

  prep_kernel<<<576, 256, 0, stream>>>(q_w, q_b, kv_w, kv_b, proj_w, fc1_w,
                                       fc2_w, wcat, bcat, projw, fc1w, fc2w);

  const int nChunks = 8 / CB;
  const int mt = CB * 98;
  for (int cchunk = 0; cchunk < nChunks; ++cchunk) {
    const size_t toff = (size_t)cchunk * Mc;
    const float* xc = x + toff * C_DIM;
    float* oc = out + toff * C_DIM;

    ln_kernel<<<(int)(Mc / 4), 256, 0, stream>>>(xc, n1g, n1b, xn);
    gemmA_kernel<0><<<dim3(1, mt), 512, 0, stream>>>(
        (const ushort*)xn, 192, (const ushort*)wcat, bcat, nullptr, qkv, 576);
    attn_kernel<<<CB * 512, 256, 0, stream>>>(rpe, qkv);
    gemmA_ln_kernel<<<dim3(1, mt), 512, 0, stream>>>(
        (const ushort*)qkv, 576, (const ushort*)projw, proj_b, xc, oc,
        n2g, n2b, xn);
    gemmA_kernel<0><<<dim3(1, mt), 512, 0, stream>>>(
        (const ushort*)xn, 192, (const ushort*)fc1w, fc1_b, nullptr, y1, 768);
    dwconv_gelu_kernel<<<dim3(7, 56, CB), 384, 0, stream>>>(
        (const ushort*)y1, dw_w, dw_b, (ushort*)y2);
    gemmB_kernel<<<dim3(1, mt), 512, 0, stream>>>(
        (const ushort*)y2, (const ushort*)fc2w, fc2_b, oc, oc);
  }
}